// Round 1
// baseline (598.794 us; speedup 1.0000x reference)
//
#include <hip/hip_runtime.h>
#include <hip/hip_bf16.h>

#define NTOK 4096
#define CIN 256
#define SCALE 0.17677669529663687f  /* 32^-0.5 */

// ---------------------------------------------------------------------------
// K1: qkv[b][o][n] = sum_c w_qkv[o][c] * x[b][c][n]   (o in [0,384))
// Tiled fp32 GEMM: 64x64 tile, BK=16, 256 threads, 4x4 per thread.
// grid (6, 64, 32)
// ---------------------------------------------------------------------------
__global__ __launch_bounds__(256) void k_qkv_gemm(const float* __restrict__ x,
                                                  const float* __restrict__ w,
                                                  float* __restrict__ qkv) {
  const int o0 = blockIdx.x * 64;
  const int n0 = blockIdx.y * 64;
  const int b  = blockIdx.z;
  const float* xb = x + (size_t)b * CIN * NTOK;
  __shared__ float As[16][64];  // [c][o]
  __shared__ float Bs[16][64];  // [c][n]
  const int t  = threadIdx.x;
  const int tx = t & 15, ty = t >> 4;
  const int wrow = t >> 2, wc4 = (t & 3) * 4;   // W tile: 64 rows x 4 float4
  const int xr = t >> 4, xc = (t & 15) * 4;     // X tile: 16 rows x 16 float4
  float acc[4][4] = {};
  for (int c0 = 0; c0 < CIN; c0 += 16) {
    float4 wv = *reinterpret_cast<const float4*>(w + (size_t)(o0 + wrow) * CIN + c0 + wc4);
    float4 xv = *reinterpret_cast<const float4*>(xb + (size_t)(c0 + xr) * NTOK + n0 + xc);
    As[wc4 + 0][wrow] = wv.x;
    As[wc4 + 1][wrow] = wv.y;
    As[wc4 + 2][wrow] = wv.z;
    As[wc4 + 3][wrow] = wv.w;
    *reinterpret_cast<float4*>(&Bs[xr][xc]) = xv;
    __syncthreads();
#pragma unroll
    for (int kk = 0; kk < 16; ++kk) {
      float a[4], bb[4];
#pragma unroll
      for (int i = 0; i < 4; ++i) a[i] = As[kk][ty * 4 + i];
#pragma unroll
      for (int j = 0; j < 4; ++j) bb[j] = Bs[kk][tx * 4 + j];
#pragma unroll
      for (int i = 0; i < 4; ++i)
#pragma unroll
        for (int j = 0; j < 4; ++j) acc[i][j] += a[i] * bb[j];
    }
    __syncthreads();
  }
  float* C = qkv + (size_t)b * 384 * NTOK;
#pragma unroll
  for (int i = 0; i < 4; ++i) {
    float4 o4 = make_float4(acc[i][0], acc[i][1], acc[i][2], acc[i][3]);
    *reinterpret_cast<float4*>(C + (size_t)(o0 + ty * 4 + i) * NTOK + n0 + tx * 4) = o4;
  }
}

// ---------------------------------------------------------------------------
// K2: k = softmax over d (32 strided values per (b,h,n)), in place.
// one thread per (b,h,n); grid 2048 x 256
// ---------------------------------------------------------------------------
__global__ __launch_bounds__(256) void k_ksoftmax(float* __restrict__ qkv) {
  const int tid = blockIdx.x * 256 + threadIdx.x;  // 524288 total
  const int b = tid >> 14;
  const int h = (tid >> 12) & 3;
  const int n = tid & 4095;
  float* p = qkv + ((size_t)(b * 384 + 128 + h * 32)) * NTOK + n;
  float vals[32];
  float m = -1e30f;
#pragma unroll
  for (int d = 0; d < 32; ++d) {
    vals[d] = p[(size_t)d * NTOK];
    m = fmaxf(m, vals[d]);
  }
  float s = 0.f;
#pragma unroll
  for (int d = 0; d < 32; ++d) {
    vals[d] = __expf(vals[d] - m);
    s += vals[d];
  }
  const float inv = 1.0f / s;
#pragma unroll
  for (int d = 0; d < 32; ++d) p[(size_t)d * NTOK] = vals[d] * inv;
}

// ---------------------------------------------------------------------------
// K3: q = softmax over n (4096 contiguous) * SCALE, in place.
// one block (256 threads) per (b,ch) row, ch in [0,128); grid 4096
// ---------------------------------------------------------------------------
__global__ __launch_bounds__(256) void k_qsoftmax(float* __restrict__ qkv) {
  const int row = blockIdx.x;  // 0..4095
  const int b = row >> 7;
  const int ch = row & 127;
  float* p = qkv + ((size_t)(b * 384 + ch)) * NTOK;
  const int t = threadIdx.x;
  float4 vals[4];
  float m = -1e30f;
#pragma unroll
  for (int i = 0; i < 4; ++i) {
    vals[i] = *reinterpret_cast<const float4*>(p + t * 4 + i * 1024);
    m = fmaxf(m, fmaxf(fmaxf(vals[i].x, vals[i].y), fmaxf(vals[i].z, vals[i].w)));
  }
  __shared__ float red[4];
#pragma unroll
  for (int off = 32; off >= 1; off >>= 1) m = fmaxf(m, __shfl_down(m, off, 64));
  if ((t & 63) == 0) red[t >> 6] = m;
  __syncthreads();
  m = fmaxf(fmaxf(red[0], red[1]), fmaxf(red[2], red[3]));
  float s = 0.f;
#pragma unroll
  for (int i = 0; i < 4; ++i) {
    vals[i].x = __expf(vals[i].x - m);
    vals[i].y = __expf(vals[i].y - m);
    vals[i].z = __expf(vals[i].z - m);
    vals[i].w = __expf(vals[i].w - m);
    s += vals[i].x + vals[i].y + vals[i].z + vals[i].w;
  }
  __syncthreads();  // red reads for m done before overwrite
#pragma unroll
  for (int off = 32; off >= 1; off >>= 1) s += __shfl_down(s, off, 64);
  if ((t & 63) == 0) red[t >> 6] = s;
  __syncthreads();
  s = red[0] + red[1] + red[2] + red[3];
  const float f = SCALE / s;
#pragma unroll
  for (int i = 0; i < 4; ++i) {
    float4 o4 = make_float4(vals[i].x * f, vals[i].y * f, vals[i].z * f, vals[i].w * f);
    *reinterpret_cast<float4*>(p + t * 4 + i * 1024) = o4;
  }
}

// ---------------------------------------------------------------------------
// K4: context_part[(bh*4+seg)][e*32+d] = sum_{n in seg} k[e][n] * v[d][n]
// grid 512 (= 128 bh x 4 seg), 256 threads; n-chunks of 128 staged in LDS.
// ---------------------------------------------------------------------------
__global__ __launch_bounds__(256) void k_context(const float* __restrict__ qkv,
                                                 float* __restrict__ ctx_part) {
  const int bh = blockIdx.x >> 2;  // 0..127
  const int seg = blockIdx.x & 3;
  const int b = bh >> 2, h = bh & 3;
  const float* kbase = qkv + ((size_t)(b * 384 + 128 + h * 32)) * NTOK + seg * 1024;
  const float* vbase = qkv + ((size_t)(b * 384 + 256 + h * 32)) * NTOK + seg * 1024;
  __shared__ float ks[32 * 129];
  __shared__ float vs[32 * 129];
  const int t = threadIdx.x;
  const int e0 = t >> 5;  // outputs (e0+8i, d)
  const int d = t & 31;
  float acc0 = 0.f, acc1 = 0.f, acc2 = 0.f, acc3 = 0.f;
  for (int n0 = 0; n0 < 1024; n0 += 128) {
    __syncthreads();
#pragma unroll
    for (int i = 0; i < 4; ++i) {
      const int fidx = t + 256 * i;  // 1024 float4s
      const int row = fidx >> 5;     // 32 float4 per row
      const int c4 = (fidx & 31) * 4;
      float4 kv = *reinterpret_cast<const float4*>(kbase + (size_t)row * NTOK + n0 + c4);
      float4 vv = *reinterpret_cast<const float4*>(vbase + (size_t)row * NTOK + n0 + c4);
      const int la = row * 129 + c4;
      ks[la + 0] = kv.x; ks[la + 1] = kv.y; ks[la + 2] = kv.z; ks[la + 3] = kv.w;
      vs[la + 0] = vv.x; vs[la + 1] = vv.y; vs[la + 2] = vv.z; vs[la + 3] = vv.w;
    }
    __syncthreads();
#pragma unroll 4
    for (int nn = 0; nn < 128; ++nn) {
      const float vd = vs[d * 129 + nn];
      acc0 += ks[(e0 + 0) * 129 + nn] * vd;
      acc1 += ks[(e0 + 8) * 129 + nn] * vd;
      acc2 += ks[(e0 + 16) * 129 + nn] * vd;
      acc3 += ks[(e0 + 24) * 129 + nn] * vd;
    }
  }
  float* outp = ctx_part + (size_t)blockIdx.x * 1024;
  outp[(e0 + 0) * 32 + d] = acc0;
  outp[(e0 + 8) * 32 + d] = acc1;
  outp[(e0 + 16) * 32 + d] = acc2;
  outp[(e0 + 24) * 32 + d] = acc3;
}

// ---------------------------------------------------------------------------
// K5: W2[b][o][h*32+e] = sum_d w_out[o][h*32+d] * ctx[b][h][e][d]
// grid 32 (one per b), 256 threads (one per o).
// ---------------------------------------------------------------------------
__global__ __launch_bounds__(256) void k_w2(const float* __restrict__ ctx_part,
                                            const float* __restrict__ w_out,
                                            float* __restrict__ W2) {
  const int b = blockIdx.x;
  const int t = threadIdx.x;  // = o
  __shared__ float ctx[4096];  // [h][e][d]
#pragma unroll
  for (int i = 0; i < 16; ++i) {
    const int idx = t + 256 * i;  // 0..4095
    const int h = idx >> 10, ed = idx & 1023;
    const float* cp = ctx_part + ((size_t)((b * 4 + h) * 4)) * 1024 + ed;
    ctx[idx] = cp[0] + cp[1024] + cp[2048] + cp[3072];
  }
  __syncthreads();
  const float* wrow = w_out + (size_t)t * 128;
  float* wout_row = W2 + ((size_t)b * 256 + t) * 128;
  float wv[32];
  for (int h = 0; h < 4; ++h) {
#pragma unroll
    for (int d = 0; d < 32; ++d) wv[d] = wrow[h * 32 + d];
#pragma unroll 4
    for (int e = 0; e < 32; ++e) {
      float a = 0.f;
#pragma unroll
      for (int d = 0; d < 32; ++d) a += wv[d] * ctx[h * 1024 + e * 32 + d];
      wout_row[h * 32 + e] = a;
    }
  }
}

// ---------------------------------------------------------------------------
// K6: out[b][o][n] = sum_{c<128} W2[b][o][c] * q'[b][c][n] + b_out[o]
// Same tiling as K1; grid (4, 64, 32).
// ---------------------------------------------------------------------------
__global__ __launch_bounds__(256) void k_out_gemm(const float* __restrict__ qkv,
                                                  const float* __restrict__ W2,
                                                  const float* __restrict__ b_out,
                                                  float* __restrict__ out) {
  const int o0 = blockIdx.x * 64;
  const int n0 = blockIdx.y * 64;
  const int b  = blockIdx.z;
  const float* A = W2 + (size_t)b * 256 * 128;
  const float* Bq = qkv + (size_t)b * 384 * NTOK;  // q channels [0,128)
  __shared__ float As[16][64];
  __shared__ float Bs[16][64];
  const int t  = threadIdx.x;
  const int tx = t & 15, ty = t >> 4;
  const int wrow = t >> 2, wc4 = (t & 3) * 4;
  const int xr = t >> 4, xc = (t & 15) * 4;
  float acc[4][4] = {};
  for (int c0 = 0; c0 < 128; c0 += 16) {
    float4 wv = *reinterpret_cast<const float4*>(A + (size_t)(o0 + wrow) * 128 + c0 + wc4);
    float4 xv = *reinterpret_cast<const float4*>(Bq + (size_t)(c0 + xr) * NTOK + n0 + xc);
    As[wc4 + 0][wrow] = wv.x;
    As[wc4 + 1][wrow] = wv.y;
    As[wc4 + 2][wrow] = wv.z;
    As[wc4 + 3][wrow] = wv.w;
    *reinterpret_cast<float4*>(&Bs[xr][xc]) = xv;
    __syncthreads();
#pragma unroll
    for (int kk = 0; kk < 16; ++kk) {
      float a[4], bb[4];
#pragma unroll
      for (int i = 0; i < 4; ++i) a[i] = As[kk][ty * 4 + i];
#pragma unroll
      for (int j = 0; j < 4; ++j) bb[j] = Bs[kk][tx * 4 + j];
#pragma unroll
      for (int i = 0; i < 4; ++i)
#pragma unroll
        for (int j = 0; j < 4; ++j) acc[i][j] += a[i] * bb[j];
    }
    __syncthreads();
  }
  float* C = out + (size_t)b * 256 * NTOK;
#pragma unroll
  for (int i = 0; i < 4; ++i) {
    const int orow = o0 + ty * 4 + i;
    const float bias = b_out[orow];
    float4 o4 = make_float4(acc[i][0] + bias, acc[i][1] + bias, acc[i][2] + bias,
                            acc[i][3] + bias);
    *reinterpret_cast<float4*>(C + (size_t)orow * NTOK + n0 + tx * 4) = o4;
  }
}

extern "C" void kernel_launch(void* const* d_in, const int* in_sizes, int n_in,
                              void* d_out, int out_size, void* d_ws, size_t ws_size,
                              hipStream_t stream) {
  const float* x     = (const float*)d_in[0];
  const float* w_qkv = (const float*)d_in[1];
  const float* w_out = (const float*)d_in[2];
  const float* b_out = (const float*)d_in[3];
  float* out = (float*)d_out;
  float* ws  = (float*)d_ws;

  float* qkv      = ws;                                  // 50331648 floats
  float* ctx_part = ws + (size_t)50331648;               // 524288 floats
  float* W2       = ws + (size_t)50331648 + 524288;      // 1048576 floats

  k_qkv_gemm<<<dim3(6, 64, 32), 256, 0, stream>>>(x, w_qkv, qkv);
  k_ksoftmax<<<2048, 256, 0, stream>>>(qkv);
  k_qsoftmax<<<4096, 256, 0, stream>>>(qkv);
  k_context<<<512, 256, 0, stream>>>(qkv, ctx_part);
  k_w2<<<32, 256, 0, stream>>>(ctx_part, w_out, W2);
  k_out_gemm<<<dim3(4, 64, 32), 256, 0, stream>>>(qkv, W2, b_out, out);
}

// Round 2
// 401.948 us; speedup vs baseline: 1.4897x; 1.4897x over previous
//
#include <hip/hip_runtime.h>
#include <hip/hip_bf16.h>

#define NTOK 4096
#define SCALE 0.17677669529663687f  /* 32^-0.5 */

using f32x4 = __attribute__((ext_vector_type(4))) float;
using s16x8 = __attribute__((ext_vector_type(8))) short;

__device__ __forceinline__ ushort bf_trunc(float f) {
  return (ushort)(__builtin_bit_cast(unsigned int, f) >> 16);
}
__device__ __forceinline__ float bf_to_f32(ushort h) {
  return __builtin_bit_cast(float, ((unsigned int)h) << 16);
}
__device__ __forceinline__ ushort bf_rne(float f) {
  unsigned int u = __builtin_bit_cast(unsigned int, f);
  u += 0x7FFFu + ((u >> 16) & 1u);
  return (ushort)(u >> 16);
}

// ---------------------------------------------------------------------------
// K0: split w_qkv (384x256 f32) into bf16 hi/lo. grid 96 x 256.
// ---------------------------------------------------------------------------
__global__ __launch_bounds__(256) void k_cvt_w(const float* __restrict__ w,
                                               ushort* __restrict__ whi,
                                               ushort* __restrict__ wlo) {
  const int i = blockIdx.x * 256 + threadIdx.x;  // 0..24575, 4 elems each
  const float4 v = reinterpret_cast<const float4*>(w)[i];
  const float fv[4] = {v.x, v.y, v.z, v.w};
  ushort4 h, l;
  ushort* hp = &h.x;
  ushort* lp = &l.x;
#pragma unroll
  for (int j = 0; j < 4; ++j) {
    const ushort hh = bf_trunc(fv[j]);
    hp[j] = hh;
    lp[j] = bf_trunc(fv[j] - bf_to_f32(hh));
  }
  reinterpret_cast<ushort4*>(whi)[i] = h;
  reinterpret_cast<ushort4*>(wlo)[i] = l;
}

// ---------------------------------------------------------------------------
// K1: qkv[b][o][n] = sum_c w[o][c] * x[b][c][n], MFMA bf16 3-term split.
// 128x128 tile, BK=32, 4 waves (2x2), 16x16x32 MFMA. grid (32, 3, 32).
// ---------------------------------------------------------------------------
__global__ __launch_bounds__(256) void k_qkv_mfma(const float* __restrict__ x,
                                                  const ushort* __restrict__ whi,
                                                  const ushort* __restrict__ wlo,
                                                  float* __restrict__ qkv) {
  const int n0 = blockIdx.x * 128;
  const int o0 = blockIdx.y * 128;
  const int b  = blockIdx.z;
  const float* xb = x + (size_t)b * 256 * NTOK;

  __shared__ ushort Ah[128 * 32];   // [o][c] bf16 hi
  __shared__ ushort Al[128 * 32];   // [o][c] bf16 lo
  __shared__ ushort Bh[128 * 40];   // [n][c] (transposed), +8 pad
  __shared__ ushort Bl[128 * 40];

  const int t = threadIdx.x;
  const int lane = t & 63;
  const int wv = t >> 6;
  const int wr = wv >> 1, wc = wv & 1;  // 2x2 wave grid, each 64x64
  const int lm = lane & 15;
  const int lk = lane >> 4;

  f32x4 acc[4][4];
#pragma unroll
  for (int i = 0; i < 4; ++i)
#pragma unroll
    for (int j = 0; j < 4; ++j) acc[i][j] = (f32x4){0.f, 0.f, 0.f, 0.f};

  for (int c0 = 0; c0 < 256; c0 += 32) {
    __syncthreads();
    // stage A (w hi/lo): 512 x 16B chunks per buffer, 2 per thread
#pragma unroll
    for (int i = 0; i < 2; ++i) {
      const int ch = t + 256 * i;
      const int row = ch >> 2, q = ch & 3;
      const size_t g = (size_t)(o0 + row) * 256 + c0 + q * 8;
      *reinterpret_cast<uint4*>(Ah + row * 32 + q * 8) =
          *reinterpret_cast<const uint4*>(whi + g);
      *reinterpret_cast<uint4*>(Al + row * 32 + q * 8) =
          *reinterpret_cast<const uint4*>(wlo + g);
    }
    // stage B (x): fp32 load, split + transpose into LDS
#pragma unroll
    for (int i = 0; i < 4; ++i) {
      const int idx = t + 256 * i;      // 1024 float4
      const int row = idx >> 5;         // c local 0..31
      const int nn = (idx & 31) * 4;    // n local
      const float4 v =
          *reinterpret_cast<const float4*>(xb + (size_t)(c0 + row) * NTOK + n0 + nn);
      const float fv[4] = {v.x, v.y, v.z, v.w};
#pragma unroll
      for (int j = 0; j < 4; ++j) {
        const ushort h = bf_trunc(fv[j]);
        Bh[(nn + j) * 40 + row] = h;
        Bl[(nn + j) * 40 + row] = bf_trunc(fv[j] - bf_to_f32(h));
      }
    }
    __syncthreads();

    s16x8 ah[4], al[4], bh[4], bl[4];
#pragma unroll
    for (int mf = 0; mf < 4; ++mf) {
      const int ar = wr * 64 + mf * 16 + lm;
      ah[mf] = *reinterpret_cast<const s16x8*>(Ah + ar * 32 + lk * 8);
      al[mf] = *reinterpret_cast<const s16x8*>(Al + ar * 32 + lk * 8);
    }
#pragma unroll
    for (int nf = 0; nf < 4; ++nf) {
      const int br = wc * 64 + nf * 16 + lm;
      bh[nf] = *reinterpret_cast<const s16x8*>(Bh + br * 40 + lk * 8);
      bl[nf] = *reinterpret_cast<const s16x8*>(Bl + br * 40 + lk * 8);
    }
#pragma unroll
    for (int mf = 0; mf < 4; ++mf)
#pragma unroll
      for (int nf = 0; nf < 4; ++nf) {
        acc[mf][nf] = __builtin_amdgcn_mfma_f32_16x16x32_bf16(ah[mf], bh[nf], acc[mf][nf], 0, 0, 0);
        acc[mf][nf] = __builtin_amdgcn_mfma_f32_16x16x32_bf16(ah[mf], bl[nf], acc[mf][nf], 0, 0, 0);
        acc[mf][nf] = __builtin_amdgcn_mfma_f32_16x16x32_bf16(al[mf], bh[nf], acc[mf][nf], 0, 0, 0);
      }
  }

  float* C = qkv + ((size_t)b * 384 + o0) * NTOK + n0;
#pragma unroll
  for (int mf = 0; mf < 4; ++mf) {
    const int row0 = wr * 64 + mf * 16 + lk * 4;
#pragma unroll
    for (int nf = 0; nf < 4; ++nf) {
      const int col = wc * 64 + nf * 16 + lm;
#pragma unroll
      for (int r = 0; r < 4; ++r)
        C[(size_t)(row0 + r) * NTOK + col] = acc[mf][nf][r];
    }
  }
}

// ---------------------------------------------------------------------------
// K2: k = softmax over d (32 strided values per (b,h,n)), in place.
// ---------------------------------------------------------------------------
__global__ __launch_bounds__(256) void k_ksoftmax(float* __restrict__ qkv) {
  const int tid = blockIdx.x * 256 + threadIdx.x;
  const int b = tid >> 14;
  const int h = (tid >> 12) & 3;
  const int n = tid & 4095;
  float* p = qkv + ((size_t)(b * 384 + 128 + h * 32)) * NTOK + n;
  float vals[32];
  float m = -1e30f;
#pragma unroll
  for (int d = 0; d < 32; ++d) {
    vals[d] = p[(size_t)d * NTOK];
    m = fmaxf(m, vals[d]);
  }
  float s = 0.f;
#pragma unroll
  for (int d = 0; d < 32; ++d) {
    vals[d] = __expf(vals[d] - m);
    s += vals[d];
  }
  const float inv = 1.0f / s;
#pragma unroll
  for (int d = 0; d < 32; ++d) p[(size_t)d * NTOK] = vals[d] * inv;
}

// ---------------------------------------------------------------------------
// K3: q = softmax over n * SCALE -> bf16 (RNE), written into the (dead)
// v region of qkv. Runs AFTER k_context. grid 4096.
// ---------------------------------------------------------------------------
__global__ __launch_bounds__(256) void k_qsoftmax(float* __restrict__ qkv) {
  const int row = blockIdx.x;
  const int b = row >> 7;
  const int ch = row & 127;
  const float* p = qkv + ((size_t)(b * 384 + ch)) * NTOK;
  ushort* qb = reinterpret_cast<ushort*>(qkv + ((size_t)b * 384 + 256) * NTOK) +
               (size_t)ch * NTOK;
  const int t = threadIdx.x;
  float4 vals[4];
  float m = -1e30f;
#pragma unroll
  for (int i = 0; i < 4; ++i) {
    vals[i] = *reinterpret_cast<const float4*>(p + t * 4 + i * 1024);
    m = fmaxf(m, fmaxf(fmaxf(vals[i].x, vals[i].y), fmaxf(vals[i].z, vals[i].w)));
  }
  __shared__ float red[4];
#pragma unroll
  for (int off = 32; off >= 1; off >>= 1) m = fmaxf(m, __shfl_down(m, off, 64));
  if ((t & 63) == 0) red[t >> 6] = m;
  __syncthreads();
  m = fmaxf(fmaxf(red[0], red[1]), fmaxf(red[2], red[3]));
  float s = 0.f;
#pragma unroll
  for (int i = 0; i < 4; ++i) {
    vals[i].x = __expf(vals[i].x - m);
    vals[i].y = __expf(vals[i].y - m);
    vals[i].z = __expf(vals[i].z - m);
    vals[i].w = __expf(vals[i].w - m);
    s += vals[i].x + vals[i].y + vals[i].z + vals[i].w;
  }
  __syncthreads();
#pragma unroll
  for (int off = 32; off >= 1; off >>= 1) s += __shfl_down(s, off, 64);
  if ((t & 63) == 0) red[t >> 6] = s;
  __syncthreads();
  s = red[0] + red[1] + red[2] + red[3];
  const float f = SCALE / s;
#pragma unroll
  for (int i = 0; i < 4; ++i) {
    ushort4 o4;
    o4.x = bf_rne(vals[i].x * f);
    o4.y = bf_rne(vals[i].y * f);
    o4.z = bf_rne(vals[i].z * f);
    o4.w = bf_rne(vals[i].w * f);
    *reinterpret_cast<ushort4*>(qb + t * 4 + i * 1024) = o4;
  }
}

// ---------------------------------------------------------------------------
// K4: context_part[(bh*4+seg)][e*32+d] = sum_{n in seg} k[e][n] * v[d][n]
// ---------------------------------------------------------------------------
__global__ __launch_bounds__(256) void k_context(const float* __restrict__ qkv,
                                                 float* __restrict__ ctx_part) {
  const int bh = blockIdx.x >> 2;
  const int seg = blockIdx.x & 3;
  const int b = bh >> 2, h = bh & 3;
  const float* kbase = qkv + ((size_t)(b * 384 + 128 + h * 32)) * NTOK + seg * 1024;
  const float* vbase = qkv + ((size_t)(b * 384 + 256 + h * 32)) * NTOK + seg * 1024;
  __shared__ float ks[32 * 129];
  __shared__ float vs[32 * 129];
  const int t = threadIdx.x;
  const int e0 = t >> 5;
  const int d = t & 31;
  float acc0 = 0.f, acc1 = 0.f, acc2 = 0.f, acc3 = 0.f;
  for (int n0 = 0; n0 < 1024; n0 += 128) {
    __syncthreads();
#pragma unroll
    for (int i = 0; i < 4; ++i) {
      const int fidx = t + 256 * i;
      const int row = fidx >> 5;
      const int c4 = (fidx & 31) * 4;
      float4 kv = *reinterpret_cast<const float4*>(kbase + (size_t)row * NTOK + n0 + c4);
      float4 vv = *reinterpret_cast<const float4*>(vbase + (size_t)row * NTOK + n0 + c4);
      const int la = row * 129 + c4;
      ks[la + 0] = kv.x; ks[la + 1] = kv.y; ks[la + 2] = kv.z; ks[la + 3] = kv.w;
      vs[la + 0] = vv.x; vs[la + 1] = vv.y; vs[la + 2] = vv.z; vs[la + 3] = vv.w;
    }
    __syncthreads();
#pragma unroll 4
    for (int nn = 0; nn < 128; ++nn) {
      const float vd = vs[d * 129 + nn];
      acc0 += ks[(e0 + 0) * 129 + nn] * vd;
      acc1 += ks[(e0 + 8) * 129 + nn] * vd;
      acc2 += ks[(e0 + 16) * 129 + nn] * vd;
      acc3 += ks[(e0 + 24) * 129 + nn] * vd;
    }
  }
  float* outp = ctx_part + (size_t)blockIdx.x * 1024;
  outp[(e0 + 0) * 32 + d] = acc0;
  outp[(e0 + 8) * 32 + d] = acc1;
  outp[(e0 + 16) * 32 + d] = acc2;
  outp[(e0 + 24) * 32 + d] = acc3;
}

// ---------------------------------------------------------------------------
// K5: W2[b][o][h*32+e] = sum_d w_out[o][h*32+d] * ctx[b][h][e][d], -> bf16
// ---------------------------------------------------------------------------
__global__ __launch_bounds__(256) void k_w2(const float* __restrict__ ctx_part,
                                            const float* __restrict__ w_out,
                                            ushort* __restrict__ W2b) {
  const int b = blockIdx.x;
  const int t = threadIdx.x;  // = o
  __shared__ float ctx[4096];
#pragma unroll
  for (int i = 0; i < 16; ++i) {
    const int idx = t + 256 * i;
    const int h = idx >> 10, ed = idx & 1023;
    const float* cp = ctx_part + ((size_t)((b * 4 + h) * 4)) * 1024 + ed;
    ctx[idx] = cp[0] + cp[1024] + cp[2048] + cp[3072];
  }
  __syncthreads();
  const float* wrow = w_out + (size_t)t * 128;
  ushort* wout_row = W2b + ((size_t)b * 256 + t) * 128;
  float wv[32];
  for (int h = 0; h < 4; ++h) {
#pragma unroll
    for (int d = 0; d < 32; ++d) wv[d] = wrow[h * 32 + d];
#pragma unroll 4
    for (int e = 0; e < 32; ++e) {
      float a = 0.f;
#pragma unroll
      for (int d = 0; d < 32; ++d) a += wv[d] * ctx[h * 1024 + e * 32 + d];
      wout_row[h * 32 + e] = bf_rne(a);
    }
  }
}

// ---------------------------------------------------------------------------
// K6: out[b][o][n] = sum_c W2b[b][o][c] * qb[b][c][n] + b_out[o], bf16 MFMA.
// grid (32, 2, 32).
// ---------------------------------------------------------------------------
__global__ __launch_bounds__(256) void k_out_mfma(const float* __restrict__ qkv,
                                                  const ushort* __restrict__ W2b,
                                                  const float* __restrict__ b_out,
                                                  float* __restrict__ out) {
  const int n0 = blockIdx.x * 128;
  const int o0 = blockIdx.y * 128;
  const int b  = blockIdx.z;
  const ushort* A  = W2b + (size_t)b * 256 * 128;
  const ushort* Bq = reinterpret_cast<const ushort*>(qkv + ((size_t)b * 384 + 256) * NTOK);

  __shared__ ushort As[128 * 32];
  __shared__ ushort Bt[128 * 40];

  const int t = threadIdx.x;
  const int lane = t & 63;
  const int wv = t >> 6;
  const int wr = wv >> 1, wc = wv & 1;
  const int lm = lane & 15;
  const int lk = lane >> 4;

  f32x4 acc[4][4];
#pragma unroll
  for (int i = 0; i < 4; ++i)
#pragma unroll
    for (int j = 0; j < 4; ++j) acc[i][j] = (f32x4){0.f, 0.f, 0.f, 0.f};

  for (int c0 = 0; c0 < 128; c0 += 32) {
    __syncthreads();
#pragma unroll
    for (int i = 0; i < 2; ++i) {
      const int ch = t + 256 * i;
      const int row = ch >> 2, q = ch & 3;
      *reinterpret_cast<uint4*>(As + row * 32 + q * 8) =
          *reinterpret_cast<const uint4*>(A + (size_t)(o0 + row) * 128 + c0 + q * 8);
    }
#pragma unroll
    for (int i = 0; i < 4; ++i) {
      const int idx = t + 256 * i;      // 1024 uint2 chunks
      const int row = idx >> 5;         // c local
      const int nn = (idx & 31) * 4;    // n local
      const uint2 v =
          *reinterpret_cast<const uint2*>(Bq + (size_t)(c0 + row) * NTOK + n0 + nn);
      Bt[(nn + 0) * 40 + row] = (ushort)(v.x & 0xFFFFu);
      Bt[(nn + 1) * 40 + row] = (ushort)(v.x >> 16);
      Bt[(nn + 2) * 40 + row] = (ushort)(v.y & 0xFFFFu);
      Bt[(nn + 3) * 40 + row] = (ushort)(v.y >> 16);
    }
    __syncthreads();

    s16x8 af[4], bf[4];
#pragma unroll
    for (int mf = 0; mf < 4; ++mf) {
      const int ar = wr * 64 + mf * 16 + lm;
      af[mf] = *reinterpret_cast<const s16x8*>(As + ar * 32 + lk * 8);
    }
#pragma unroll
    for (int nf = 0; nf < 4; ++nf) {
      const int br = wc * 64 + nf * 16 + lm;
      bf[nf] = *reinterpret_cast<const s16x8*>(Bt + br * 40 + lk * 8);
    }
#pragma unroll
    for (int mf = 0; mf < 4; ++mf)
#pragma unroll
      for (int nf = 0; nf < 4; ++nf)
        acc[mf][nf] = __builtin_amdgcn_mfma_f32_16x16x32_bf16(af[mf], bf[nf], acc[mf][nf], 0, 0, 0);
  }

  float* C = out + ((size_t)b * 256 + o0) * NTOK + n0;
#pragma unroll
  for (int mf = 0; mf < 4; ++mf) {
    const int row0 = wr * 64 + mf * 16 + lk * 4;
#pragma unroll
    for (int nf = 0; nf < 4; ++nf) {
      const int col = wc * 64 + nf * 16 + lm;
#pragma unroll
      for (int r = 0; r < 4; ++r) {
        const float bias = b_out[o0 + row0 + r];
        C[(size_t)(row0 + r) * NTOK + col] = acc[mf][nf][r] + bias;
      }
    }
  }
}

extern "C" void kernel_launch(void* const* d_in, const int* in_sizes, int n_in,
                              void* d_out, int out_size, void* d_ws, size_t ws_size,
                              hipStream_t stream) {
  const float* x     = (const float*)d_in[0];
  const float* w_qkv = (const float*)d_in[1];
  const float* w_out = (const float*)d_in[2];
  const float* b_out = (const float*)d_in[3];
  float* out = (float*)d_out;
  float* ws  = (float*)d_ws;

  float*  qkv      = ws;                         // 50331648 floats (201.3 MB)
  float*  ctx_part = ws + (size_t)50331648;      // 524288 floats (2 MB)
  ushort* whi      = (ushort*)ctx_part;          // aliases ctx_part (live K1 only)
  ushort* wlo      = whi + 98304;
  ushort* W2b      = (ushort*)(ws + (size_t)50855936);  // 1048576 ushorts (2 MB)

  k_cvt_w<<<96, 256, 0, stream>>>(w_qkv, whi, wlo);
  k_qkv_mfma<<<dim3(32, 3, 32), 256, 0, stream>>>(x, whi, wlo, qkv);
  k_ksoftmax<<<2048, 256, 0, stream>>>(qkv);
  k_context<<<512, 256, 0, stream>>>(qkv, ctx_part);
  k_qsoftmax<<<4096, 256, 0, stream>>>(qkv);   // writes q bf16 into dead v region
  k_w2<<<32, 256, 0, stream>>>(ctx_part, w_out, W2b);
  k_out_mfma<<<dim3(32, 2, 32), 256, 0, stream>>>(qkv, W2b, b_out, out);
}

// Round 3
// 279.470 us; speedup vs baseline: 2.1426x; 1.4383x over previous
//
#include <hip/hip_runtime.h>
#include <hip/hip_bf16.h>

#define NTOK 4096
#define SCALE 0.17677669529663687f  /* 32^-0.5 */

// 16B-chunk XOR swizzle within a 64B (32-ushort) LDS row: bijective, keeps
// 8-ushort K-slices contiguous, spreads banks across rows (write==read map).
#define SWZ(r) ((((r) >> 1) ^ ((r) >> 3)) & 3)

using f32x4 = __attribute__((ext_vector_type(4))) float;
using s16x8 = __attribute__((ext_vector_type(8))) short;

__device__ __forceinline__ ushort bf_trunc(float f) {
  return (ushort)(__builtin_bit_cast(unsigned int, f) >> 16);
}
__device__ __forceinline__ float bf_to_f32(ushort h) {
  return __builtin_bit_cast(float, ((unsigned int)h) << 16);
}
__device__ __forceinline__ ushort bf_rne(float f) {
  unsigned int u = __builtin_bit_cast(unsigned int, f);
  u += 0x7FFFu + ((u >> 16) & 1u);
  return (ushort)(u >> 16);
}

// ---------------------------------------------------------------------------
// K0: split w_qkv (384x256 f32) into bf16 hi/lo. grid 96 x 256.
// ---------------------------------------------------------------------------
__global__ __launch_bounds__(256) void k_cvt_w(const float* __restrict__ w,
                                               ushort* __restrict__ whi,
                                               ushort* __restrict__ wlo) {
  const int i = blockIdx.x * 256 + threadIdx.x;
  const float4 v = reinterpret_cast<const float4*>(w)[i];
  const float fv[4] = {v.x, v.y, v.z, v.w};
  ushort4 h, l;
  ushort* hp = &h.x;
  ushort* lp = &l.x;
#pragma unroll
  for (int j = 0; j < 4; ++j) {
    const ushort hh = bf_trunc(fv[j]);
    hp[j] = hh;
    lp[j] = bf_trunc(fv[j] - bf_to_f32(hh));
  }
  reinterpret_cast<ushort4*>(whi)[i] = h;
  reinterpret_cast<ushort4*>(wlo)[i] = l;
}

// ---------------------------------------------------------------------------
// K1: qkv[b][o][n] = sum_c w[o][c] * x[b][c][n], MFMA bf16 3-term split.
// 128x128 tile, BK=32, 4 waves (2x2), 16x16x32 MFMA. grid (32, 3, 32).
// LDS: dense [row][32] ushort tiles with SWZ 16B-chunk swizzle.
// ---------------------------------------------------------------------------
__global__ __launch_bounds__(256) void k_qkv_mfma(const float* __restrict__ x,
                                                  const ushort* __restrict__ whi,
                                                  const ushort* __restrict__ wlo,
                                                  float* __restrict__ qkv) {
  const int n0 = blockIdx.x * 128;
  const int o0 = blockIdx.y * 128;
  const int b  = blockIdx.z;
  const float* xb = x + (size_t)b * 256 * NTOK;

  __shared__ ushort Ah[128 * 32];
  __shared__ ushort Al[128 * 32];
  __shared__ ushort Bh[128 * 32];
  __shared__ ushort Bl[128 * 32];

  const int t = threadIdx.x;
  const int lane = t & 63;
  const int wv = t >> 6;
  const int wr = wv >> 1, wc = wv & 1;
  const int lm = lane & 15;
  const int lk = lane >> 4;

  // loop-invariant fragment LDS offsets (swizzled)
  int aoff[4], boff[4];
#pragma unroll
  for (int mf = 0; mf < 4; ++mf) {
    const int ar = wr * 64 + mf * 16 + lm;
    aoff[mf] = ar * 32 + 8 * (lk ^ SWZ(ar));
  }
#pragma unroll
  for (int nf = 0; nf < 4; ++nf) {
    const int br = wc * 64 + nf * 16 + lm;
    boff[nf] = br * 32 + 8 * (lk ^ SWZ(br));
  }
  // loop-invariant staging offsets
  int ast[2], arow[2], aq[2];
#pragma unroll
  for (int i = 0; i < 2; ++i) {
    const int ch = t + 256 * i;
    arow[i] = ch >> 2;
    aq[i] = ch & 3;
    ast[i] = arow[i] * 32 + 8 * (aq[i] ^ SWZ(arow[i]));
  }
  int bst[4], bn[4], bcg[4];
#pragma unroll
  for (int i = 0; i < 4; ++i) {
    const int idx = t + 256 * i;
    bn[i] = idx & 127;
    bcg[i] = idx >> 7;
    bst[i] = bn[i] * 32 + 8 * ((bcg[i] >> 1) ^ SWZ(bn[i])) + (bcg[i] & 1) * 4;
  }

  f32x4 acc[4][4];
#pragma unroll
  for (int i = 0; i < 4; ++i)
#pragma unroll
    for (int j = 0; j < 4; ++j) acc[i][j] = (f32x4){0.f, 0.f, 0.f, 0.f};

  for (int c0 = 0; c0 < 256; c0 += 32) {
    __syncthreads();
    // stage A (w hi/lo): one 16B chunk per thread per buffer, x2
#pragma unroll
    for (int i = 0; i < 2; ++i) {
      const size_t g = (size_t)(o0 + arow[i]) * 256 + c0 + aq[i] * 8;
      *reinterpret_cast<uint4*>(Ah + ast[i]) =
          *reinterpret_cast<const uint4*>(whi + g);
      *reinterpret_cast<uint4*>(Al + ast[i]) =
          *reinterpret_cast<const uint4*>(wlo + g);
    }
    // stage B (x): thread = (n, 4 consecutive c); coalesced dword loads,
    // split hi/lo, ushort4 writes (swizzled chunk)
#pragma unroll
    for (int i = 0; i < 4; ++i) {
      const float* gp = xb + (size_t)(c0 + bcg[i] * 4) * NTOK + n0 + bn[i];
      const float f0 = gp[0];
      const float f1 = gp[NTOK];
      const float f2 = gp[2 * NTOK];
      const float f3 = gp[3 * NTOK];
      ushort4 h, l;
      h.x = bf_trunc(f0); l.x = bf_trunc(f0 - bf_to_f32(h.x));
      h.y = bf_trunc(f1); l.y = bf_trunc(f1 - bf_to_f32(h.y));
      h.z = bf_trunc(f2); l.z = bf_trunc(f2 - bf_to_f32(h.z));
      h.w = bf_trunc(f3); l.w = bf_trunc(f3 - bf_to_f32(h.w));
      *reinterpret_cast<ushort4*>(Bh + bst[i]) = h;
      *reinterpret_cast<ushort4*>(Bl + bst[i]) = l;
    }
    __syncthreads();

    s16x8 ah[4], al[4], bh[4], bl[4];
#pragma unroll
    for (int mf = 0; mf < 4; ++mf) {
      ah[mf] = *reinterpret_cast<const s16x8*>(Ah + aoff[mf]);
      al[mf] = *reinterpret_cast<const s16x8*>(Al + aoff[mf]);
    }
#pragma unroll
    for (int nf = 0; nf < 4; ++nf) {
      bh[nf] = *reinterpret_cast<const s16x8*>(Bh + boff[nf]);
      bl[nf] = *reinterpret_cast<const s16x8*>(Bl + boff[nf]);
    }
#pragma unroll
    for (int mf = 0; mf < 4; ++mf)
#pragma unroll
      for (int nf = 0; nf < 4; ++nf) {
        acc[mf][nf] = __builtin_amdgcn_mfma_f32_16x16x32_bf16(ah[mf], bh[nf], acc[mf][nf], 0, 0, 0);
        acc[mf][nf] = __builtin_amdgcn_mfma_f32_16x16x32_bf16(ah[mf], bl[nf], acc[mf][nf], 0, 0, 0);
        acc[mf][nf] = __builtin_amdgcn_mfma_f32_16x16x32_bf16(al[mf], bh[nf], acc[mf][nf], 0, 0, 0);
      }
  }

  float* C = qkv + ((size_t)b * 384 + o0) * NTOK + n0;
#pragma unroll
  for (int mf = 0; mf < 4; ++mf) {
    const int row0 = wr * 64 + mf * 16 + lk * 4;
#pragma unroll
    for (int nf = 0; nf < 4; ++nf) {
      const int col = wc * 64 + nf * 16 + lm;
#pragma unroll
      for (int r = 0; r < 4; ++r)
        C[(size_t)(row0 + r) * NTOK + col] = acc[mf][nf][r];
    }
  }
}

// ---------------------------------------------------------------------------
// K2: k = softmax over d (32 strided values per (b,h,n)), in place.
// ---------------------------------------------------------------------------
__global__ __launch_bounds__(256) void k_ksoftmax(float* __restrict__ qkv) {
  const int tid = blockIdx.x * 256 + threadIdx.x;
  const int b = tid >> 14;
  const int h = (tid >> 12) & 3;
  const int n = tid & 4095;
  float* p = qkv + ((size_t)(b * 384 + 128 + h * 32)) * NTOK + n;
  float vals[32];
  float m = -1e30f;
#pragma unroll
  for (int d = 0; d < 32; ++d) {
    vals[d] = p[(size_t)d * NTOK];
    m = fmaxf(m, vals[d]);
  }
  float s = 0.f;
#pragma unroll
  for (int d = 0; d < 32; ++d) {
    vals[d] = __expf(vals[d] - m);
    s += vals[d];
  }
  const float inv = 1.0f / s;
#pragma unroll
  for (int d = 0; d < 32; ++d) p[(size_t)d * NTOK] = vals[d] * inv;
}

// ---------------------------------------------------------------------------
// K3: q = softmax over n * SCALE -> bf16 (RNE), into dead v region.
// ---------------------------------------------------------------------------
__global__ __launch_bounds__(256) void k_qsoftmax(float* __restrict__ qkv) {
  const int row = blockIdx.x;
  const int b = row >> 7;
  const int ch = row & 127;
  const float* p = qkv + ((size_t)(b * 384 + ch)) * NTOK;
  ushort* qb = reinterpret_cast<ushort*>(qkv + ((size_t)b * 384 + 256) * NTOK) +
               (size_t)ch * NTOK;
  const int t = threadIdx.x;
  float4 vals[4];
  float m = -1e30f;
#pragma unroll
  for (int i = 0; i < 4; ++i) {
    vals[i] = *reinterpret_cast<const float4*>(p + t * 4 + i * 1024);
    m = fmaxf(m, fmaxf(fmaxf(vals[i].x, vals[i].y), fmaxf(vals[i].z, vals[i].w)));
  }
  __shared__ float red[4];
#pragma unroll
  for (int off = 32; off >= 1; off >>= 1) m = fmaxf(m, __shfl_down(m, off, 64));
  if ((t & 63) == 0) red[t >> 6] = m;
  __syncthreads();
  m = fmaxf(fmaxf(red[0], red[1]), fmaxf(red[2], red[3]));
  float s = 0.f;
#pragma unroll
  for (int i = 0; i < 4; ++i) {
    vals[i].x = __expf(vals[i].x - m);
    vals[i].y = __expf(vals[i].y - m);
    vals[i].z = __expf(vals[i].z - m);
    vals[i].w = __expf(vals[i].w - m);
    s += vals[i].x + vals[i].y + vals[i].z + vals[i].w;
  }
  __syncthreads();
#pragma unroll
  for (int off = 32; off >= 1; off >>= 1) s += __shfl_down(s, off, 64);
  if ((t & 63) == 0) red[t >> 6] = s;
  __syncthreads();
  s = red[0] + red[1] + red[2] + red[3];
  const float f = SCALE / s;
#pragma unroll
  for (int i = 0; i < 4; ++i) {
    ushort4 o4;
    o4.x = bf_rne(vals[i].x * f);
    o4.y = bf_rne(vals[i].y * f);
    o4.z = bf_rne(vals[i].z * f);
    o4.w = bf_rne(vals[i].w * f);
    *reinterpret_cast<ushort4*>(qb + t * 4 + i * 1024) = o4;
  }
}

// ---------------------------------------------------------------------------
// K4: context_part[(bh*4+seg)][e*32+d] = sum_{n in seg} k[e][n] * v[d][n]
// ---------------------------------------------------------------------------
__global__ __launch_bounds__(256) void k_context(const float* __restrict__ qkv,
                                                 float* __restrict__ ctx_part) {
  const int bh = blockIdx.x >> 2;
  const int seg = blockIdx.x & 3;
  const int b = bh >> 2, h = bh & 3;
  const float* kbase = qkv + ((size_t)(b * 384 + 128 + h * 32)) * NTOK + seg * 1024;
  const float* vbase = qkv + ((size_t)(b * 384 + 256 + h * 32)) * NTOK + seg * 1024;
  __shared__ float ks[32 * 129];
  __shared__ float vs[32 * 129];
  const int t = threadIdx.x;
  const int e0 = t >> 5;
  const int d = t & 31;
  float acc0 = 0.f, acc1 = 0.f, acc2 = 0.f, acc3 = 0.f;
  for (int n0 = 0; n0 < 1024; n0 += 128) {
    __syncthreads();
#pragma unroll
    for (int i = 0; i < 4; ++i) {
      const int fidx = t + 256 * i;
      const int row = fidx >> 5;
      const int c4 = (fidx & 31) * 4;
      float4 kv = *reinterpret_cast<const float4*>(kbase + (size_t)row * NTOK + n0 + c4);
      float4 vv = *reinterpret_cast<const float4*>(vbase + (size_t)row * NTOK + n0 + c4);
      const int la = row * 129 + c4;
      ks[la + 0] = kv.x; ks[la + 1] = kv.y; ks[la + 2] = kv.z; ks[la + 3] = kv.w;
      vs[la + 0] = vv.x; vs[la + 1] = vv.y; vs[la + 2] = vv.z; vs[la + 3] = vv.w;
    }
    __syncthreads();
#pragma unroll 4
    for (int nn = 0; nn < 128; ++nn) {
      const float vd = vs[d * 129 + nn];
      acc0 += ks[(e0 + 0) * 129 + nn] * vd;
      acc1 += ks[(e0 + 8) * 129 + nn] * vd;
      acc2 += ks[(e0 + 16) * 129 + nn] * vd;
      acc3 += ks[(e0 + 24) * 129 + nn] * vd;
    }
  }
  float* outp = ctx_part + (size_t)blockIdx.x * 1024;
  outp[(e0 + 0) * 32 + d] = acc0;
  outp[(e0 + 8) * 32 + d] = acc1;
  outp[(e0 + 16) * 32 + d] = acc2;
  outp[(e0 + 24) * 32 + d] = acc3;
}

// ---------------------------------------------------------------------------
// K5: W2[b][o][h*32+e] = sum_d w_out[o][h*32+d] * ctx[b][h][e][d], -> bf16
// ---------------------------------------------------------------------------
__global__ __launch_bounds__(256) void k_w2(const float* __restrict__ ctx_part,
                                            const float* __restrict__ w_out,
                                            ushort* __restrict__ W2b) {
  const int b = blockIdx.x;
  const int t = threadIdx.x;
  __shared__ float ctx[4096];
#pragma unroll
  for (int i = 0; i < 16; ++i) {
    const int idx = t + 256 * i;
    const int h = idx >> 10, ed = idx & 1023;
    const float* cp = ctx_part + ((size_t)((b * 4 + h) * 4)) * 1024 + ed;
    ctx[idx] = cp[0] + cp[1024] + cp[2048] + cp[3072];
  }
  __syncthreads();
  const float* wrow = w_out + (size_t)t * 128;
  ushort* wout_row = W2b + ((size_t)b * 256 + t) * 128;
  float wv[32];
  for (int h = 0; h < 4; ++h) {
#pragma unroll
    for (int d = 0; d < 32; ++d) wv[d] = wrow[h * 32 + d];
#pragma unroll 4
    for (int e = 0; e < 32; ++e) {
      float a = 0.f;
#pragma unroll
      for (int d = 0; d < 32; ++d) a += wv[d] * ctx[h * 1024 + e * 32 + d];
      wout_row[h * 32 + e] = bf_rne(a);
    }
  }
}

// ---------------------------------------------------------------------------
// K6: out[b][o][n] = sum_c W2b[b][o][c] * qb[b][c][n] + b_out[o], bf16 MFMA.
// grid (32, 2, 32). Same swizzled-LDS scheme as K1.
// ---------------------------------------------------------------------------
__global__ __launch_bounds__(256) void k_out_mfma(const float* __restrict__ qkv,
                                                  const ushort* __restrict__ W2b,
                                                  const float* __restrict__ b_out,
                                                  float* __restrict__ out) {
  const int n0 = blockIdx.x * 128;
  const int o0 = blockIdx.y * 128;
  const int b  = blockIdx.z;
  const ushort* A  = W2b + (size_t)b * 256 * 128;
  const ushort* Bq = reinterpret_cast<const ushort*>(qkv + ((size_t)b * 384 + 256) * NTOK);

  __shared__ ushort As[128 * 32];
  __shared__ ushort Bt[128 * 32];

  const int t = threadIdx.x;
  const int lane = t & 63;
  const int wv = t >> 6;
  const int wr = wv >> 1, wc = wv & 1;
  const int lm = lane & 15;
  const int lk = lane >> 4;

  int aoff[4], boff[4];
#pragma unroll
  for (int mf = 0; mf < 4; ++mf) {
    const int ar = wr * 64 + mf * 16 + lm;
    aoff[mf] = ar * 32 + 8 * (lk ^ SWZ(ar));
  }
#pragma unroll
  for (int nf = 0; nf < 4; ++nf) {
    const int br = wc * 64 + nf * 16 + lm;
    boff[nf] = br * 32 + 8 * (lk ^ SWZ(br));
  }
  int ast[2], arow[2], aq[2];
#pragma unroll
  for (int i = 0; i < 2; ++i) {
    const int ch = t + 256 * i;
    arow[i] = ch >> 2;
    aq[i] = ch & 3;
    ast[i] = arow[i] * 32 + 8 * (aq[i] ^ SWZ(arow[i]));
  }
  int bst[4], bn[4], bcg[4];
#pragma unroll
  for (int i = 0; i < 4; ++i) {
    const int idx = t + 256 * i;
    bn[i] = idx & 127;
    bcg[i] = idx >> 7;
    bst[i] = bn[i] * 32 + 8 * ((bcg[i] >> 1) ^ SWZ(bn[i])) + (bcg[i] & 1) * 4;
  }

  f32x4 acc[4][4];
#pragma unroll
  for (int i = 0; i < 4; ++i)
#pragma unroll
    for (int j = 0; j < 4; ++j) acc[i][j] = (f32x4){0.f, 0.f, 0.f, 0.f};

  for (int c0 = 0; c0 < 128; c0 += 32) {
    __syncthreads();
#pragma unroll
    for (int i = 0; i < 2; ++i) {
      *reinterpret_cast<uint4*>(As + ast[i]) = *reinterpret_cast<const uint4*>(
          A + (size_t)(o0 + arow[i]) * 128 + c0 + aq[i] * 8);
    }
#pragma unroll
    for (int i = 0; i < 4; ++i) {
      const ushort* gp = Bq + (size_t)(c0 + bcg[i] * 4) * NTOK + n0 + bn[i];
      ushort4 hvec;
      hvec.x = gp[0];
      hvec.y = gp[NTOK];
      hvec.z = gp[2 * NTOK];
      hvec.w = gp[3 * NTOK];
      *reinterpret_cast<ushort4*>(Bt + bst[i]) = hvec;
    }
    __syncthreads();

    s16x8 af[4], bf[4];
#pragma unroll
    for (int mf = 0; mf < 4; ++mf)
      af[mf] = *reinterpret_cast<const s16x8*>(As + aoff[mf]);
#pragma unroll
    for (int nf = 0; nf < 4; ++nf)
      bf[nf] = *reinterpret_cast<const s16x8*>(Bt + boff[nf]);
#pragma unroll
    for (int mf = 0; mf < 4; ++mf)
#pragma unroll
      for (int nf = 0; nf < 4; ++nf)
        acc[mf][nf] = __builtin_amdgcn_mfma_f32_16x16x32_bf16(af[mf], bf[nf], acc[mf][nf], 0, 0, 0);
  }

  float* C = out + ((size_t)b * 256 + o0) * NTOK + n0;
#pragma unroll
  for (int mf = 0; mf < 4; ++mf) {
    const int row0 = wr * 64 + mf * 16 + lk * 4;
#pragma unroll
    for (int nf = 0; nf < 4; ++nf) {
      const int col = wc * 64 + nf * 16 + lm;
#pragma unroll
      for (int r = 0; r < 4; ++r) {
        const float bias = b_out[o0 + row0 + r];
        C[(size_t)(row0 + r) * NTOK + col] = acc[mf][nf][r] + bias;
      }
    }
  }
}

extern "C" void kernel_launch(void* const* d_in, const int* in_sizes, int n_in,
                              void* d_out, int out_size, void* d_ws, size_t ws_size,
                              hipStream_t stream) {
  const float* x     = (const float*)d_in[0];
  const float* w_qkv = (const float*)d_in[1];
  const float* w_out = (const float*)d_in[2];
  const float* b_out = (const float*)d_in[3];
  float* out = (float*)d_out;
  float* ws  = (float*)d_ws;

  float*  qkv      = ws;                         // 50331648 floats (201.3 MB)
  float*  ctx_part = ws + (size_t)50331648;      // 524288 floats (2 MB)
  ushort* whi      = (ushort*)ctx_part;          // aliases ctx_part (live K1 only)
  ushort* wlo      = whi + 98304;
  ushort* W2b      = (ushort*)(ws + (size_t)50855936);  // 1048576 ushorts (2 MB)

  k_cvt_w<<<96, 256, 0, stream>>>(w_qkv, whi, wlo);
  k_qkv_mfma<<<dim3(32, 3, 32), 256, 0, stream>>>(x, whi, wlo, qkv);
  k_ksoftmax<<<2048, 256, 0, stream>>>(qkv);
  k_context<<<512, 256, 0, stream>>>(qkv, ctx_part);
  k_qsoftmax<<<4096, 256, 0, stream>>>(qkv);   // writes q bf16 into dead v region
  k_w2<<<32, 256, 0, stream>>>(ctx_part, w_out, W2b);
  k_out_mfma<<<dim3(32, 2, 32), 256, 0, stream>>>(qkv, W2b, b_out, out);
}

// Round 4
// 274.342 us; speedup vs baseline: 2.1827x; 1.0187x over previous
//
#include <hip/hip_runtime.h>
#include <hip/hip_bf16.h>

#define NTOK 4096
#define SCALE 0.17677669529663687f  /* 32^-0.5 */

// 16B-chunk XOR swizzle within a 64B (32-ushort) LDS row.
#define SWZ(r) ((((r) >> 1) ^ ((r) >> 3)) & 3)

using f32x4 = __attribute__((ext_vector_type(4))) float;
using s16x8 = __attribute__((ext_vector_type(8))) short;

__device__ __forceinline__ ushort bf_trunc(float f) {
  return (ushort)(__builtin_bit_cast(unsigned int, f) >> 16);
}
__device__ __forceinline__ float bf_to_f32(ushort h) {
  return __builtin_bit_cast(float, ((unsigned int)h) << 16);
}
__device__ __forceinline__ ushort bf_rne(float f) {
  unsigned int u = __builtin_bit_cast(unsigned int, f);
  u += 0x7FFFu + ((u >> 16) & 1u);
  return (ushort)(u >> 16);
}
// async global->LDS, 16B per lane; LDS dest = wave-uniform base + lane*16.
__device__ __forceinline__ void gl_lds16(const ushort* g, ushort* l) {
  __builtin_amdgcn_global_load_lds(
      (const __attribute__((address_space(1))) unsigned int*)g,
      (__attribute__((address_space(3))) unsigned int*)l, 16, 0, 0);
}

// ---------------------------------------------------------------------------
// K0: split w_qkv (384x256 f32) into bf16 hi/lo. grid 96 x 256.
// ---------------------------------------------------------------------------
__global__ __launch_bounds__(256) void k_cvt_w(const float* __restrict__ w,
                                               ushort* __restrict__ whi,
                                               ushort* __restrict__ wlo) {
  const int i = blockIdx.x * 256 + threadIdx.x;
  const float4 v = reinterpret_cast<const float4*>(w)[i];
  const float fv[4] = {v.x, v.y, v.z, v.w};
  ushort4 h, l;
  ushort* hp = &h.x;
  ushort* lp = &l.x;
#pragma unroll
  for (int j = 0; j < 4; ++j) {
    const ushort hh = bf_trunc(fv[j]);
    hp[j] = hh;
    lp[j] = bf_trunc(fv[j] - bf_to_f32(hh));
  }
  reinterpret_cast<ushort4*>(whi)[i] = h;
  reinterpret_cast<ushort4*>(wlo)[i] = l;
}

// ---------------------------------------------------------------------------
// K1: qkv[b][o][n] = sum_c w[o][c] * x[b][c][n], MFMA bf16 3-term split.
// 128x128 tile, BK=32, 4 waves (2x2), 16x16x32 MFMA. grid (32, 3, 32).
// 2-phase double-buffered: A via global_load_lds (pre-swizzled source),
// B reg-staged with loads issued before the MFMA phase. 1 barrier/iter.
// y==1 blocks (k region) apply softmax-over-d in the epilogue.
// ---------------------------------------------------------------------------
__global__ __launch_bounds__(256) void k_qkv_mfma(const float* __restrict__ x,
                                                  const ushort* __restrict__ whi,
                                                  const ushort* __restrict__ wlo,
                                                  float* __restrict__ qkv) {
  const int n0 = blockIdx.x * 128;
  const int o0 = blockIdx.y * 128;
  const int b  = blockIdx.z;
  const float* xb = x + (size_t)b * 256 * NTOK;

  __shared__ ushort Ah[2 * 4096];
  __shared__ ushort Al[2 * 4096];
  __shared__ ushort Bh[2 * 4096];
  __shared__ ushort Bl[2 * 4096];

  const int t = threadIdx.x;
  const int lane = t & 63;
  const int wv = t >> 6;
  const int wr = wv >> 1, wc = wv & 1;
  const int lm = lane & 15;
  const int lk = lane >> 4;

  // fragment read offsets (swizzled)
  int aoff[4], boff[4];
#pragma unroll
  for (int mf = 0; mf < 4; ++mf) {
    const int ar = wr * 64 + mf * 16 + lm;
    aoff[mf] = ar * 32 + 8 * (lk ^ SWZ(ar));
  }
#pragma unroll
  for (int nf = 0; nf < 4; ++nf) {
    const int br = wc * 64 + nf * 16 + lm;
    boff[nf] = br * 32 + 8 * (lk ^ SWZ(br));
  }
  // A gload: slot s -> holds global chunk (row=s>>2, q=(s&3)^SWZ(row)).
  const int as1 = t, as2 = t + 256;
  const int ar1 = as1 >> 2, gq1 = (as1 & 3) ^ SWZ(ar1);
  const int ar2 = as2 >> 2, gq2 = (as2 & 3) ^ SWZ(ar2);
  const size_t ga1 = (size_t)(o0 + ar1) * 256 + gq1 * 8;
  const size_t ga2 = (size_t)(o0 + ar2) * 256 + gq2 * 8;
  const int lbase1 = (t >> 6) * 512;         // ushort offset of wave chunk 1
  const int lbase2 = 2048 + (t >> 6) * 512;  // ushort offset of wave chunk 2
  // B staging indices
  int bst[4], bn[4], bcg[4];
#pragma unroll
  for (int i = 0; i < 4; ++i) {
    const int idx = t + 256 * i;
    bn[i] = idx & 127;
    bcg[i] = idx >> 7;
    bst[i] = bn[i] * 32 + 8 * ((bcg[i] >> 1) ^ SWZ(bn[i])) + (bcg[i] & 1) * 4;
  }

  f32x4 acc[4][4];
#pragma unroll
  for (int i = 0; i < 4; ++i)
#pragma unroll
    for (int j = 0; j < 4; ++j) acc[i][j] = (f32x4){0.f, 0.f, 0.f, 0.f};

  // ---- prologue: stage c0 = 0 into buffer 0 ----
  {
    gl_lds16(whi + ga1, Ah + lbase1);
    gl_lds16(whi + ga2, Ah + lbase2);
    gl_lds16(wlo + ga1, Al + lbase1);
    gl_lds16(wlo + ga2, Al + lbase2);
    float pre[16];
#pragma unroll
    for (int i = 0; i < 4; ++i)
#pragma unroll
      for (int j = 0; j < 4; ++j)
        pre[i * 4 + j] = xb[(size_t)(bcg[i] * 4 + j) * NTOK + n0 + bn[i]];
#pragma unroll
    for (int i = 0; i < 4; ++i) {
      ushort4 h, l;
      h.x = bf_trunc(pre[i*4+0]); l.x = bf_trunc(pre[i*4+0] - bf_to_f32(h.x));
      h.y = bf_trunc(pre[i*4+1]); l.y = bf_trunc(pre[i*4+1] - bf_to_f32(h.y));
      h.z = bf_trunc(pre[i*4+2]); l.z = bf_trunc(pre[i*4+2] - bf_to_f32(h.z));
      h.w = bf_trunc(pre[i*4+3]); l.w = bf_trunc(pre[i*4+3] - bf_to_f32(h.w));
      *reinterpret_cast<ushort4*>(Bh + bst[i]) = h;
      *reinterpret_cast<ushort4*>(Bl + bst[i]) = l;
    }
  }
  __syncthreads();

  // ---- main loop: 8 K-steps, one barrier each ----
  for (int it = 0; it < 8; ++it) {
    const int cur = (it & 1) * 4096;
    const int nx  = 4096 - cur;
    float pre[16];
    if (it < 7) {
      const size_t c1 = (size_t)(it + 1) * 32;
      gl_lds16(whi + ga1 + c1, Ah + nx + lbase1);
      gl_lds16(whi + ga2 + c1, Ah + nx + lbase2);
      gl_lds16(wlo + ga1 + c1, Al + nx + lbase1);
      gl_lds16(wlo + ga2 + c1, Al + nx + lbase2);
#pragma unroll
      for (int i = 0; i < 4; ++i)
#pragma unroll
        for (int j = 0; j < 4; ++j)
          pre[i * 4 + j] = xb[(c1 + bcg[i] * 4 + j) * NTOK + n0 + bn[i]];
    }

    s16x8 ah[4], al[4], bh[4], bl[4];
#pragma unroll
    for (int mf = 0; mf < 4; ++mf) {
      ah[mf] = *reinterpret_cast<const s16x8*>(Ah + cur + aoff[mf]);
      al[mf] = *reinterpret_cast<const s16x8*>(Al + cur + aoff[mf]);
    }
#pragma unroll
    for (int nf = 0; nf < 4; ++nf) {
      bh[nf] = *reinterpret_cast<const s16x8*>(Bh + cur + boff[nf]);
      bl[nf] = *reinterpret_cast<const s16x8*>(Bl + cur + boff[nf]);
    }
#pragma unroll
    for (int mf = 0; mf < 4; ++mf)
#pragma unroll
      for (int nf = 0; nf < 4; ++nf) {
        acc[mf][nf] = __builtin_amdgcn_mfma_f32_16x16x32_bf16(ah[mf], bh[nf], acc[mf][nf], 0, 0, 0);
        acc[mf][nf] = __builtin_amdgcn_mfma_f32_16x16x32_bf16(ah[mf], bl[nf], acc[mf][nf], 0, 0, 0);
        acc[mf][nf] = __builtin_amdgcn_mfma_f32_16x16x32_bf16(al[mf], bh[nf], acc[mf][nf], 0, 0, 0);
      }

    if (it < 7) {
#pragma unroll
      for (int i = 0; i < 4; ++i) {
        ushort4 h, l;
        h.x = bf_trunc(pre[i*4+0]); l.x = bf_trunc(pre[i*4+0] - bf_to_f32(h.x));
        h.y = bf_trunc(pre[i*4+1]); l.y = bf_trunc(pre[i*4+1] - bf_to_f32(h.y));
        h.z = bf_trunc(pre[i*4+2]); l.z = bf_trunc(pre[i*4+2] - bf_to_f32(h.z));
        h.w = bf_trunc(pre[i*4+3]); l.w = bf_trunc(pre[i*4+3] - bf_to_f32(h.w));
        *reinterpret_cast<ushort4*>(Bh + nx + bst[i]) = h;
        *reinterpret_cast<ushort4*>(Bl + nx + bst[i]) = l;
      }
    }
    __syncthreads();
  }

  // ---- epilogue: fused softmax-over-d for the k o-tile (y==1) ----
  if (blockIdx.y == 1) {
    // wave rows: wr*64 + mf*16 + lk*4 + r; head group g covers mf in {2g,2g+1}
    // => 8 in-lane values x 4 lk-lanes = 32 d-values per column.
#pragma unroll
    for (int nf = 0; nf < 4; ++nf) {
#pragma unroll
      for (int g = 0; g < 2; ++g) {
        float m = -1e30f;
#pragma unroll
        for (int mm = 0; mm < 2; ++mm)
#pragma unroll
          for (int r = 0; r < 4; ++r)
            m = fmaxf(m, acc[g * 2 + mm][nf][r]);
        m = fmaxf(m, __shfl_xor(m, 16, 64));
        m = fmaxf(m, __shfl_xor(m, 32, 64));
        float s = 0.f;
#pragma unroll
        for (int mm = 0; mm < 2; ++mm)
#pragma unroll
          for (int r = 0; r < 4; ++r) {
            const float e = __expf(acc[g * 2 + mm][nf][r] - m);
            acc[g * 2 + mm][nf][r] = e;
            s += e;
          }
        s += __shfl_xor(s, 16, 64);
        s += __shfl_xor(s, 32, 64);
        const float inv = 1.0f / s;
#pragma unroll
        for (int mm = 0; mm < 2; ++mm)
#pragma unroll
          for (int r = 0; r < 4; ++r) acc[g * 2 + mm][nf][r] *= inv;
      }
    }
  }

  float* C = qkv + ((size_t)b * 384 + o0) * NTOK + n0;
#pragma unroll
  for (int mf = 0; mf < 4; ++mf) {
    const int row0 = wr * 64 + mf * 16 + lk * 4;
#pragma unroll
    for (int nf = 0; nf < 4; ++nf) {
      const int col = wc * 64 + nf * 16 + lm;
#pragma unroll
      for (int r = 0; r < 4; ++r)
        C[(size_t)(row0 + r) * NTOK + col] = acc[mf][nf][r];
    }
  }
}

// ---------------------------------------------------------------------------
// K3: q = softmax over n * SCALE -> bf16 (RNE), into dead v region.
// ---------------------------------------------------------------------------
__global__ __launch_bounds__(256) void k_qsoftmax(float* __restrict__ qkv) {
  const int row = blockIdx.x;
  const int b = row >> 7;
  const int ch = row & 127;
  const float* p = qkv + ((size_t)(b * 384 + ch)) * NTOK;
  ushort* qb = reinterpret_cast<ushort*>(qkv + ((size_t)b * 384 + 256) * NTOK) +
               (size_t)ch * NTOK;
  const int t = threadIdx.x;
  float4 vals[4];
  float m = -1e30f;
#pragma unroll
  for (int i = 0; i < 4; ++i) {
    vals[i] = *reinterpret_cast<const float4*>(p + t * 4 + i * 1024);
    m = fmaxf(m, fmaxf(fmaxf(vals[i].x, vals[i].y), fmaxf(vals[i].z, vals[i].w)));
  }
  __shared__ float red[4];
#pragma unroll
  for (int off = 32; off >= 1; off >>= 1) m = fmaxf(m, __shfl_down(m, off, 64));
  if ((t & 63) == 0) red[t >> 6] = m;
  __syncthreads();
  m = fmaxf(fmaxf(red[0], red[1]), fmaxf(red[2], red[3]));
  float s = 0.f;
#pragma unroll
  for (int i = 0; i < 4; ++i) {
    vals[i].x = __expf(vals[i].x - m);
    vals[i].y = __expf(vals[i].y - m);
    vals[i].z = __expf(vals[i].z - m);
    vals[i].w = __expf(vals[i].w - m);
    s += vals[i].x + vals[i].y + vals[i].z + vals[i].w;
  }
  __syncthreads();
#pragma unroll
  for (int off = 32; off >= 1; off >>= 1) s += __shfl_down(s, off, 64);
  if ((t & 63) == 0) red[t >> 6] = s;
  __syncthreads();
  s = red[0] + red[1] + red[2] + red[3];
  const float f = SCALE / s;
#pragma unroll
  for (int i = 0; i < 4; ++i) {
    ushort4 o4;
    o4.x = bf_rne(vals[i].x * f);
    o4.y = bf_rne(vals[i].y * f);
    o4.z = bf_rne(vals[i].z * f);
    o4.w = bf_rne(vals[i].w * f);
    *reinterpret_cast<ushort4*>(qb + t * 4 + i * 1024) = o4;
  }
}

// ---------------------------------------------------------------------------
// K4: context_part[(bh*4+seg)][e*32+d] = sum_{n in seg} k[e][n] * v[d][n]
// ---------------------------------------------------------------------------
__global__ __launch_bounds__(256) void k_context(const float* __restrict__ qkv,
                                                 float* __restrict__ ctx_part) {
  const int bh = blockIdx.x >> 2;
  const int seg = blockIdx.x & 3;
  const int b = bh >> 2, h = bh & 3;
  const float* kbase = qkv + ((size_t)(b * 384 + 128 + h * 32)) * NTOK + seg * 1024;
  const float* vbase = qkv + ((size_t)(b * 384 + 256 + h * 32)) * NTOK + seg * 1024;
  __shared__ float ks[32 * 129];
  __shared__ float vs[32 * 129];
  const int t = threadIdx.x;
  const int e0 = t >> 5;
  const int d = t & 31;
  float acc0 = 0.f, acc1 = 0.f, acc2 = 0.f, acc3 = 0.f;
  for (int n0 = 0; n0 < 1024; n0 += 128) {
    __syncthreads();
#pragma unroll
    for (int i = 0; i < 4; ++i) {
      const int fidx = t + 256 * i;
      const int row = fidx >> 5;
      const int c4 = (fidx & 31) * 4;
      float4 kv = *reinterpret_cast<const float4*>(kbase + (size_t)row * NTOK + n0 + c4);
      float4 vv = *reinterpret_cast<const float4*>(vbase + (size_t)row * NTOK + n0 + c4);
      const int la = row * 129 + c4;
      ks[la + 0] = kv.x; ks[la + 1] = kv.y; ks[la + 2] = kv.z; ks[la + 3] = kv.w;
      vs[la + 0] = vv.x; vs[la + 1] = vv.y; vs[la + 2] = vv.z; vs[la + 3] = vv.w;
    }
    __syncthreads();
#pragma unroll 4
    for (int nn = 0; nn < 128; ++nn) {
      const float vd = vs[d * 129 + nn];
      acc0 += ks[(e0 + 0) * 129 + nn] * vd;
      acc1 += ks[(e0 + 8) * 129 + nn] * vd;
      acc2 += ks[(e0 + 16) * 129 + nn] * vd;
      acc3 += ks[(e0 + 24) * 129 + nn] * vd;
    }
  }
  float* outp = ctx_part + (size_t)blockIdx.x * 1024;
  outp[(e0 + 0) * 32 + d] = acc0;
  outp[(e0 + 8) * 32 + d] = acc1;
  outp[(e0 + 16) * 32 + d] = acc2;
  outp[(e0 + 24) * 32 + d] = acc3;
}

// ---------------------------------------------------------------------------
// K5: W2[b][o][h*32+e] = sum_d w_out[o][h*32+d] * ctx[b][h][e][d], -> bf16
// ---------------------------------------------------------------------------
__global__ __launch_bounds__(256) void k_w2(const float* __restrict__ ctx_part,
                                            const float* __restrict__ w_out,
                                            ushort* __restrict__ W2b) {
  const int b = blockIdx.x;
  const int t = threadIdx.x;
  __shared__ float ctx[4096];
#pragma unroll
  for (int i = 0; i < 16; ++i) {
    const int idx = t + 256 * i;
    const int h = idx >> 10, ed = idx & 1023;
    const float* cp = ctx_part + ((size_t)((b * 4 + h) * 4)) * 1024 + ed;
    ctx[idx] = cp[0] + cp[1024] + cp[2048] + cp[3072];
  }
  __syncthreads();
  const float* wrow = w_out + (size_t)t * 128;
  ushort* wout_row = W2b + ((size_t)b * 256 + t) * 128;
  float wv[32];
  for (int h = 0; h < 4; ++h) {
#pragma unroll
    for (int d = 0; d < 32; ++d) wv[d] = wrow[h * 32 + d];
#pragma unroll 4
    for (int e = 0; e < 32; ++e) {
      float a = 0.f;
#pragma unroll
      for (int d = 0; d < 32; ++d) a += wv[d] * ctx[h * 1024 + e * 32 + d];
      wout_row[h * 32 + e] = bf_rne(a);
    }
  }
}

// ---------------------------------------------------------------------------
// K6: out[b][o][n] = sum_c W2b[b][o][c] * qb[b][c][n] + b_out[o], bf16 MFMA.
// grid (32, 2, 32). Swizzled LDS, single-buffer (unchanged from r3).
// ---------------------------------------------------------------------------
__global__ __launch_bounds__(256) void k_out_mfma(const float* __restrict__ qkv,
                                                  const ushort* __restrict__ W2b,
                                                  const float* __restrict__ b_out,
                                                  float* __restrict__ out) {
  const int n0 = blockIdx.x * 128;
  const int o0 = blockIdx.y * 128;
  const int b  = blockIdx.z;
  const ushort* A  = W2b + (size_t)b * 256 * 128;
  const ushort* Bq = reinterpret_cast<const ushort*>(qkv + ((size_t)b * 384 + 256) * NTOK);

  __shared__ ushort As[128 * 32];
  __shared__ ushort Bt[128 * 32];

  const int t = threadIdx.x;
  const int lane = t & 63;
  const int wv = t >> 6;
  const int wr = wv >> 1, wc = wv & 1;
  const int lm = lane & 15;
  const int lk = lane >> 4;

  int aoff[4], boff[4];
#pragma unroll
  for (int mf = 0; mf < 4; ++mf) {
    const int ar = wr * 64 + mf * 16 + lm;
    aoff[mf] = ar * 32 + 8 * (lk ^ SWZ(ar));
  }
#pragma unroll
  for (int nf = 0; nf < 4; ++nf) {
    const int br = wc * 64 + nf * 16 + lm;
    boff[nf] = br * 32 + 8 * (lk ^ SWZ(br));
  }
  int ast[2], arow[2], aq[2];
#pragma unroll
  for (int i = 0; i < 2; ++i) {
    const int ch = t + 256 * i;
    arow[i] = ch >> 2;
    aq[i] = ch & 3;
    ast[i] = arow[i] * 32 + 8 * (aq[i] ^ SWZ(arow[i]));
  }
  int bst[4], bn[4], bcg[4];
#pragma unroll
  for (int i = 0; i < 4; ++i) {
    const int idx = t + 256 * i;
    bn[i] = idx & 127;
    bcg[i] = idx >> 7;
    bst[i] = bn[i] * 32 + 8 * ((bcg[i] >> 1) ^ SWZ(bn[i])) + (bcg[i] & 1) * 4;
  }

  f32x4 acc[4][4];
#pragma unroll
  for (int i = 0; i < 4; ++i)
#pragma unroll
    for (int j = 0; j < 4; ++j) acc[i][j] = (f32x4){0.f, 0.f, 0.f, 0.f};

  for (int c0 = 0; c0 < 128; c0 += 32) {
    __syncthreads();
#pragma unroll
    for (int i = 0; i < 2; ++i) {
      *reinterpret_cast<uint4*>(As + ast[i]) = *reinterpret_cast<const uint4*>(
          A + (size_t)(o0 + arow[i]) * 128 + c0 + aq[i] * 8);
    }
#pragma unroll
    for (int i = 0; i < 4; ++i) {
      const ushort* gp = Bq + (size_t)(c0 + bcg[i] * 4) * NTOK + n0 + bn[i];
      ushort4 hvec;
      hvec.x = gp[0];
      hvec.y = gp[NTOK];
      hvec.z = gp[2 * NTOK];
      hvec.w = gp[3 * NTOK];
      *reinterpret_cast<ushort4*>(Bt + bst[i]) = hvec;
    }
    __syncthreads();

    s16x8 af[4], bf[4];
#pragma unroll
    for (int mf = 0; mf < 4; ++mf)
      af[mf] = *reinterpret_cast<const s16x8*>(As + aoff[mf]);
#pragma unroll
    for (int nf = 0; nf < 4; ++nf)
      bf[nf] = *reinterpret_cast<const s16x8*>(Bt + boff[nf]);
#pragma unroll
    for (int mf = 0; mf < 4; ++mf)
#pragma unroll
      for (int nf = 0; nf < 4; ++nf)
        acc[mf][nf] = __builtin_amdgcn_mfma_f32_16x16x32_bf16(af[mf], bf[nf], acc[mf][nf], 0, 0, 0);
  }

  float* C = out + ((size_t)b * 256 + o0) * NTOK + n0;
#pragma unroll
  for (int mf = 0; mf < 4; ++mf) {
    const int row0 = wr * 64 + mf * 16 + lk * 4;
#pragma unroll
    for (int nf = 0; nf < 4; ++nf) {
      const int col = wc * 64 + nf * 16 + lm;
#pragma unroll
      for (int r = 0; r < 4; ++r) {
        const float bias = b_out[o0 + row0 + r];
        C[(size_t)(row0 + r) * NTOK + col] = acc[mf][nf][r] + bias;
      }
    }
  }
}

extern "C" void kernel_launch(void* const* d_in, const int* in_sizes, int n_in,
                              void* d_out, int out_size, void* d_ws, size_t ws_size,
                              hipStream_t stream) {
  const float* x     = (const float*)d_in[0];
  const float* w_qkv = (const float*)d_in[1];
  const float* w_out = (const float*)d_in[2];
  const float* b_out = (const float*)d_in[3];
  float* out = (float*)d_out;
  float* ws  = (float*)d_ws;

  float*  qkv      = ws;                         // 50331648 floats (201.3 MB)
  float*  ctx_part = ws + (size_t)50331648;      // 524288 floats (2 MB)
  ushort* whi      = (ushort*)ctx_part;          // aliases ctx_part (live K1 only)
  ushort* wlo      = whi + 98304;
  ushort* W2b      = (ushort*)(ws + (size_t)50855936);  // 1048576 ushorts (2 MB)

  k_cvt_w<<<96, 256, 0, stream>>>(w_qkv, whi, wlo);
  k_qkv_mfma<<<dim3(32, 3, 32), 256, 0, stream>>>(x, whi, wlo, qkv);  // +fused k-softmax
  k_context<<<512, 256, 0, stream>>>(qkv, ctx_part);
  k_qsoftmax<<<4096, 256, 0, stream>>>(qkv);   // writes q bf16 into dead v region
  k_w2<<<32, 256, 0, stream>>>(ctx_part, w_out, W2b);
  k_out_mfma<<<dim3(32, 2, 32), 256, 0, stream>>>(qkv, W2b, b_out, out);
}

// Round 5
// 229.618 us; speedup vs baseline: 2.6078x; 1.1948x over previous
//
#include <hip/hip_runtime.h>
#include <hip/hip_bf16.h>

#define NTOK 4096
#define SCALE 0.17677669529663687f  /* 32^-0.5 */

// 16B-chunk XOR swizzle within a 64B (32-ushort) LDS row.
#define SWZ(r) ((((r) >> 1) ^ ((r) >> 3)) & 3)

using f32x4 = __attribute__((ext_vector_type(4))) float;
using s16x8 = __attribute__((ext_vector_type(8))) short;

__device__ __forceinline__ ushort bf_trunc(float f) {
  return (ushort)(__builtin_bit_cast(unsigned int, f) >> 16);
}
__device__ __forceinline__ float bf_to_f32(ushort h) {
  return __builtin_bit_cast(float, ((unsigned int)h) << 16);
}
__device__ __forceinline__ ushort bf_rne(float f) {
  unsigned int u = __builtin_bit_cast(unsigned int, f);
  u += 0x7FFFu + ((u >> 16) & 1u);
  return (ushort)(u >> 16);
}
// async global->LDS, 16B per lane; LDS dest = wave-uniform base + lane*16.
__device__ __forceinline__ void gl_lds16(const ushort* g, ushort* l) {
  __builtin_amdgcn_global_load_lds(
      (const __attribute__((address_space(1))) unsigned int*)g,
      (__attribute__((address_space(3))) unsigned int*)l, 16, 0, 0);
}

// ---------------------------------------------------------------------------
// K0: split w_qkv (384x256 f32) into bf16 hi/lo. grid 96 x 256.
// ---------------------------------------------------------------------------
__global__ __launch_bounds__(256) void k_cvt_w(const float* __restrict__ w,
                                               ushort* __restrict__ whi,
                                               ushort* __restrict__ wlo) {
  const int i = blockIdx.x * 256 + threadIdx.x;
  const float4 v = reinterpret_cast<const float4*>(w)[i];
  const float fv[4] = {v.x, v.y, v.z, v.w};
  ushort4 h, l;
  ushort* hp = &h.x;
  ushort* lp = &l.x;
#pragma unroll
  for (int j = 0; j < 4; ++j) {
    const ushort hh = bf_trunc(fv[j]);
    hp[j] = hh;
    lp[j] = bf_trunc(fv[j] - bf_to_f32(hh));
  }
  reinterpret_cast<ushort4*>(whi)[i] = h;
  reinterpret_cast<ushort4*>(wlo)[i] = l;
}

// ---------------------------------------------------------------------------
// K1: qkv = w_qkv @ x, MFMA bf16 3-term split. 128x128 tile, BK=32, 4 waves,
// single-buffer 32KB LDS, 2 barriers/iter, T14 early B-prefetch.
// Epilogue: y==0 -> q fp32; y==1 -> softmax-over-d -> k bf16; y==2 -> v bf16.
// grid (32, 3, 32).
// ---------------------------------------------------------------------------
__global__ __launch_bounds__(256) void k_qkv_mfma(const float* __restrict__ x,
                                                  const ushort* __restrict__ whi,
                                                  const ushort* __restrict__ wlo,
                                                  float* __restrict__ q_f32,
                                                  ushort* __restrict__ kb,
                                                  ushort* __restrict__ vb) {
  const int n0 = blockIdx.x * 128;
  const int o0 = blockIdx.y * 128;
  const int b  = blockIdx.z;
  const float* xb = x + (size_t)b * 256 * NTOK;

  __shared__ ushort Ah[4096];
  __shared__ ushort Al[4096];
  __shared__ ushort Bh[4096];
  __shared__ ushort Bl[4096];

  const int t = threadIdx.x;
  const int lane = t & 63;
  const int wv = t >> 6;
  const int wr = wv >> 1, wc = wv & 1;
  const int lm = lane & 15;
  const int lk = lane >> 4;

  // fragment read offsets (swizzled)
  int aoff[4], boff[4];
#pragma unroll
  for (int mf = 0; mf < 4; ++mf) {
    const int ar = wr * 64 + mf * 16 + lm;
    aoff[mf] = ar * 32 + 8 * (lk ^ SWZ(ar));
  }
#pragma unroll
  for (int nf = 0; nf < 4; ++nf) {
    const int br = wc * 64 + nf * 16 + lm;
    boff[nf] = br * 32 + 8 * (lk ^ SWZ(br));
  }
  // A gl_lds addressing: slot s holds global chunk (row=s>>2, q=(s&3)^SWZ(row))
  const int as1 = t, as2 = t + 256;
  const int ar1 = as1 >> 2, gq1 = (as1 & 3) ^ SWZ(ar1);
  const int ar2 = as2 >> 2, gq2 = (as2 & 3) ^ SWZ(ar2);
  const size_t ga1 = (size_t)(o0 + ar1) * 256 + gq1 * 8;
  const size_t ga2 = (size_t)(o0 + ar2) * 256 + gq2 * 8;
  const int lbase1 = wv * 512;          // ushort offset of wave chunk 1
  const int lbase2 = 2048 + wv * 512;   // ushort offset of wave chunk 2
  // B staging indices
  int bst[4], bn[4], bcg[4];
#pragma unroll
  for (int i = 0; i < 4; ++i) {
    const int idx = t + 256 * i;
    bn[i] = idx & 127;
    bcg[i] = idx >> 7;
    bst[i] = bn[i] * 32 + 8 * ((bcg[i] >> 1) ^ SWZ(bn[i])) + (bcg[i] & 1) * 4;
  }

  f32x4 acc[4][4];
#pragma unroll
  for (int i = 0; i < 4; ++i)
#pragma unroll
    for (int j = 0; j < 4; ++j) acc[i][j] = (f32x4){0.f, 0.f, 0.f, 0.f};

  // prologue: prefetch B(0) into regs
  float pre[16];
#pragma unroll
  for (int i = 0; i < 4; ++i)
#pragma unroll
    for (int j = 0; j < 4; ++j)
      pre[i * 4 + j] = xb[(size_t)(bcg[i] * 4 + j) * NTOK + n0 + bn[i]];

  for (int it = 0; it < 8; ++it) {
    const size_t c0 = (size_t)it * 32;
    // ---- write phase: A async->LDS, B split from regs ----
    gl_lds16(whi + ga1 + c0, Ah + lbase1);
    gl_lds16(whi + ga2 + c0, Ah + lbase2);
    gl_lds16(wlo + ga1 + c0, Al + lbase1);
    gl_lds16(wlo + ga2 + c0, Al + lbase2);
#pragma unroll
    for (int i = 0; i < 4; ++i) {
      ushort4 h, l;
      h.x = bf_trunc(pre[i*4+0]); l.x = bf_trunc(pre[i*4+0] - bf_to_f32(h.x));
      h.y = bf_trunc(pre[i*4+1]); l.y = bf_trunc(pre[i*4+1] - bf_to_f32(h.y));
      h.z = bf_trunc(pre[i*4+2]); l.z = bf_trunc(pre[i*4+2] - bf_to_f32(h.z));
      h.w = bf_trunc(pre[i*4+3]); l.w = bf_trunc(pre[i*4+3] - bf_to_f32(h.w));
      *reinterpret_cast<ushort4*>(Bh + bst[i]) = h;
      *reinterpret_cast<ushort4*>(Bl + bst[i]) = l;
    }
    __syncthreads();
    // ---- prefetch B(it+1): issued before MFMA, completes during it ----
    if (it < 7) {
      const size_t c1 = c0 + 32;
#pragma unroll
      for (int i = 0; i < 4; ++i)
#pragma unroll
        for (int j = 0; j < 4; ++j)
          pre[i * 4 + j] = xb[(c1 + bcg[i] * 4 + j) * NTOK + n0 + bn[i]];
    }
    // ---- MFMA phase ----
    s16x8 ah[4], al[4], bh[4], bl[4];
#pragma unroll
    for (int mf = 0; mf < 4; ++mf) {
      ah[mf] = *reinterpret_cast<const s16x8*>(Ah + aoff[mf]);
      al[mf] = *reinterpret_cast<const s16x8*>(Al + aoff[mf]);
    }
#pragma unroll
    for (int nf = 0; nf < 4; ++nf) {
      bh[nf] = *reinterpret_cast<const s16x8*>(Bh + boff[nf]);
      bl[nf] = *reinterpret_cast<const s16x8*>(Bl + boff[nf]);
    }
#pragma unroll
    for (int mf = 0; mf < 4; ++mf)
#pragma unroll
      for (int nf = 0; nf < 4; ++nf) {
        acc[mf][nf] = __builtin_amdgcn_mfma_f32_16x16x32_bf16(ah[mf], bh[nf], acc[mf][nf], 0, 0, 0);
        acc[mf][nf] = __builtin_amdgcn_mfma_f32_16x16x32_bf16(ah[mf], bl[nf], acc[mf][nf], 0, 0, 0);
        acc[mf][nf] = __builtin_amdgcn_mfma_f32_16x16x32_bf16(al[mf], bh[nf], acc[mf][nf], 0, 0, 0);
      }
    __syncthreads();
  }

  // ---- epilogue ----
  if (blockIdx.y == 0) {
    float* C = q_f32 + (size_t)b * 128 * NTOK + n0;
#pragma unroll
    for (int mf = 0; mf < 4; ++mf) {
      const int row0 = wr * 64 + mf * 16 + lk * 4;
#pragma unroll
      for (int nf = 0; nf < 4; ++nf) {
        const int col = wc * 64 + nf * 16 + lm;
#pragma unroll
        for (int r = 0; r < 4; ++r)
          C[(size_t)(row0 + r) * NTOK + col] = acc[mf][nf][r];
      }
    }
  } else if (blockIdx.y == 1) {
    // fused softmax over d: wave rows wr*64+mf*16+lk*4+r; head group g = mf>>1
#pragma unroll
    for (int nf = 0; nf < 4; ++nf) {
#pragma unroll
      for (int g = 0; g < 2; ++g) {
        float m = -1e30f;
#pragma unroll
        for (int mm = 0; mm < 2; ++mm)
#pragma unroll
          for (int r = 0; r < 4; ++r)
            m = fmaxf(m, acc[g * 2 + mm][nf][r]);
        m = fmaxf(m, __shfl_xor(m, 16, 64));
        m = fmaxf(m, __shfl_xor(m, 32, 64));
        float s = 0.f;
#pragma unroll
        for (int mm = 0; mm < 2; ++mm)
#pragma unroll
          for (int r = 0; r < 4; ++r) {
            const float e = __expf(acc[g * 2 + mm][nf][r] - m);
            acc[g * 2 + mm][nf][r] = e;
            s += e;
          }
        s += __shfl_xor(s, 16, 64);
        s += __shfl_xor(s, 32, 64);
        const float inv = 1.0f / s;
#pragma unroll
        for (int mm = 0; mm < 2; ++mm)
#pragma unroll
          for (int r = 0; r < 4; ++r) acc[g * 2 + mm][nf][r] *= inv;
      }
    }
    ushort* C = kb + (size_t)b * 128 * NTOK + n0;
#pragma unroll
    for (int mf = 0; mf < 4; ++mf) {
      const int row0 = wr * 64 + mf * 16 + lk * 4;
#pragma unroll
      for (int nf = 0; nf < 4; ++nf) {
        const int col = wc * 64 + nf * 16 + lm;
#pragma unroll
        for (int r = 0; r < 4; ++r)
          C[(size_t)(row0 + r) * NTOK + col] = bf_rne(acc[mf][nf][r]);
      }
    }
  } else {
    ushort* C = vb + (size_t)b * 128 * NTOK + n0;
#pragma unroll
    for (int mf = 0; mf < 4; ++mf) {
      const int row0 = wr * 64 + mf * 16 + lk * 4;
#pragma unroll
      for (int nf = 0; nf < 4; ++nf) {
        const int col = wc * 64 + nf * 16 + lm;
#pragma unroll
        for (int r = 0; r < 4; ++r)
          C[(size_t)(row0 + r) * NTOK + col] = bf_rne(acc[mf][nf][r]);
      }
    }
  }
}

// ---------------------------------------------------------------------------
// K2: context partials via bf16 MFMA. block = (b,h), 4 waves = 4 n-segments.
// ctx_part[(bh*4+w)][e*32+d] = sum_{n in seg w} k[e][n]*v[d][n]. grid 128.
// ---------------------------------------------------------------------------
__global__ __launch_bounds__(256) void k_context_mfma(const ushort* __restrict__ kb,
                                                      const ushort* __restrict__ vb,
                                                      float* __restrict__ ctx_part) {
  const int bh = blockIdx.x;            // b*4+h ; row base = 32*bh
  const int w = threadIdx.x >> 6;
  const int lane = threadIdx.x & 63;
  const int lm = lane & 15, lk = lane >> 4;
  const ushort* kp = kb + (size_t)bh * 32 * NTOK + (size_t)w * 1024;
  const ushort* vp = vb + (size_t)bh * 32 * NTOK + (size_t)w * 1024;
  f32x4 acc[2][2];
#pragma unroll
  for (int i = 0; i < 2; ++i)
#pragma unroll
    for (int j = 0; j < 2; ++j) acc[i][j] = (f32x4){0.f, 0.f, 0.f, 0.f};
#pragma unroll 4
  for (int ks = 0; ks < 32; ++ks) {
    const int coff = ks * 32 + lk * 8;
    const s16x8 a0 = *reinterpret_cast<const s16x8*>(kp + (size_t)lm * NTOK + coff);
    const s16x8 a1 = *reinterpret_cast<const s16x8*>(kp + (size_t)(16 + lm) * NTOK + coff);
    const s16x8 b0 = *reinterpret_cast<const s16x8*>(vp + (size_t)lm * NTOK + coff);
    const s16x8 b1 = *reinterpret_cast<const s16x8*>(vp + (size_t)(16 + lm) * NTOK + coff);
    acc[0][0] = __builtin_amdgcn_mfma_f32_16x16x32_bf16(a0, b0, acc[0][0], 0, 0, 0);
    acc[0][1] = __builtin_amdgcn_mfma_f32_16x16x32_bf16(a0, b1, acc[0][1], 0, 0, 0);
    acc[1][0] = __builtin_amdgcn_mfma_f32_16x16x32_bf16(a1, b0, acc[1][0], 0, 0, 0);
    acc[1][1] = __builtin_amdgcn_mfma_f32_16x16x32_bf16(a1, b1, acc[1][1], 0, 0, 0);
  }
  float* op = ctx_part + ((size_t)bh * 4 + w) * 1024;
#pragma unroll
  for (int et = 0; et < 2; ++et)
#pragma unroll
    for (int dt = 0; dt < 2; ++dt)
#pragma unroll
      for (int r = 0; r < 4; ++r)
        op[(et * 16 + lk * 4 + r) * 32 + dt * 16 + lm] = acc[et][dt][r];
}

// ---------------------------------------------------------------------------
// K3: q = softmax over n * SCALE -> bf16 (RNE). grid 4096.
// ---------------------------------------------------------------------------
__global__ __launch_bounds__(256) void k_qsoftmax(const float* __restrict__ q_f32,
                                                  ushort* __restrict__ qb) {
  const int row = blockIdx.x;
  const float* p = q_f32 + (size_t)row * NTOK;
  ushort* qbp = qb + (size_t)row * NTOK;
  const int t = threadIdx.x;
  float4 vals[4];
  float m = -1e30f;
#pragma unroll
  for (int i = 0; i < 4; ++i) {
    vals[i] = *reinterpret_cast<const float4*>(p + t * 4 + i * 1024);
    m = fmaxf(m, fmaxf(fmaxf(vals[i].x, vals[i].y), fmaxf(vals[i].z, vals[i].w)));
  }
  __shared__ float red[4];
#pragma unroll
  for (int off = 32; off >= 1; off >>= 1) m = fmaxf(m, __shfl_down(m, off, 64));
  if ((t & 63) == 0) red[t >> 6] = m;
  __syncthreads();
  m = fmaxf(fmaxf(red[0], red[1]), fmaxf(red[2], red[3]));
  float s = 0.f;
#pragma unroll
  for (int i = 0; i < 4; ++i) {
    vals[i].x = __expf(vals[i].x - m);
    vals[i].y = __expf(vals[i].y - m);
    vals[i].z = __expf(vals[i].z - m);
    vals[i].w = __expf(vals[i].w - m);
    s += vals[i].x + vals[i].y + vals[i].z + vals[i].w;
  }
  __syncthreads();
#pragma unroll
  for (int off = 32; off >= 1; off >>= 1) s += __shfl_down(s, off, 64);
  if ((t & 63) == 0) red[t >> 6] = s;
  __syncthreads();
  s = red[0] + red[1] + red[2] + red[3];
  const float f = SCALE / s;
#pragma unroll
  for (int i = 0; i < 4; ++i) {
    ushort4 o4;
    o4.x = bf_rne(vals[i].x * f);
    o4.y = bf_rne(vals[i].y * f);
    o4.z = bf_rne(vals[i].z * f);
    o4.w = bf_rne(vals[i].w * f);
    *reinterpret_cast<ushort4*>(qbp + t * 4 + i * 1024) = o4;
  }
}

// ---------------------------------------------------------------------------
// K5: W2[b][o][h*32+e] = sum_d w_out[o][h*32+d] * ctx[b][h][e][d], -> bf16
// ---------------------------------------------------------------------------
__global__ __launch_bounds__(256) void k_w2(const float* __restrict__ ctx_part,
                                            const float* __restrict__ w_out,
                                            ushort* __restrict__ W2b) {
  const int b = blockIdx.x;
  const int t = threadIdx.x;
  __shared__ float ctx[4096];
#pragma unroll
  for (int i = 0; i < 16; ++i) {
    const int idx = t + 256 * i;
    const int h = idx >> 10, ed = idx & 1023;
    const float* cp = ctx_part + ((size_t)((b * 4 + h) * 4)) * 1024 + ed;
    ctx[idx] = cp[0] + cp[1024] + cp[2048] + cp[3072];
  }
  __syncthreads();
  const float* wrow = w_out + (size_t)t * 128;
  ushort* wout_row = W2b + ((size_t)b * 256 + t) * 128;
  float wv[32];
  for (int h = 0; h < 4; ++h) {
#pragma unroll
    for (int d = 0; d < 32; ++d) wv[d] = wrow[h * 32 + d];
#pragma unroll 4
    for (int e = 0; e < 32; ++e) {
      float a = 0.f;
#pragma unroll
      for (int d = 0; d < 32; ++d) a += wv[d] * ctx[h * 1024 + e * 32 + d];
      wout_row[h * 32 + e] = bf_rne(a);
    }
  }
}

// ---------------------------------------------------------------------------
// K6: out[b][o][n] = sum_c W2b[b][o][c] * qb[b][c][n] + b_out[o], bf16 MFMA.
// grid (32, 2, 32). Swizzled LDS, single-buffer.
// ---------------------------------------------------------------------------
__global__ __launch_bounds__(256) void k_out_mfma(const ushort* __restrict__ qb,
                                                  const ushort* __restrict__ W2b,
                                                  const float* __restrict__ b_out,
                                                  float* __restrict__ out) {
  const int n0 = blockIdx.x * 128;
  const int o0 = blockIdx.y * 128;
  const int b  = blockIdx.z;
  const ushort* A  = W2b + (size_t)b * 256 * 128;
  const ushort* Bq = qb + (size_t)b * 128 * NTOK;

  __shared__ ushort As[128 * 32];
  __shared__ ushort Bt[128 * 32];

  const int t = threadIdx.x;
  const int lane = t & 63;
  const int wv = t >> 6;
  const int wr = wv >> 1, wc = wv & 1;
  const int lm = lane & 15;
  const int lk = lane >> 4;

  int aoff[4], boff[4];
#pragma unroll
  for (int mf = 0; mf < 4; ++mf) {
    const int ar = wr * 64 + mf * 16 + lm;
    aoff[mf] = ar * 32 + 8 * (lk ^ SWZ(ar));
  }
#pragma unroll
  for (int nf = 0; nf < 4; ++nf) {
    const int br = wc * 64 + nf * 16 + lm;
    boff[nf] = br * 32 + 8 * (lk ^ SWZ(br));
  }
  int ast[2], arow[2], aq[2];
#pragma unroll
  for (int i = 0; i < 2; ++i) {
    const int ch = t + 256 * i;
    arow[i] = ch >> 2;
    aq[i] = ch & 3;
    ast[i] = arow[i] * 32 + 8 * (aq[i] ^ SWZ(arow[i]));
  }
  int bst[4], bn[4], bcg[4];
#pragma unroll
  for (int i = 0; i < 4; ++i) {
    const int idx = t + 256 * i;
    bn[i] = idx & 127;
    bcg[i] = idx >> 7;
    bst[i] = bn[i] * 32 + 8 * ((bcg[i] >> 1) ^ SWZ(bn[i])) + (bcg[i] & 1) * 4;
  }

  f32x4 acc[4][4];
#pragma unroll
  for (int i = 0; i < 4; ++i)
#pragma unroll
    for (int j = 0; j < 4; ++j) acc[i][j] = (f32x4){0.f, 0.f, 0.f, 0.f};

  for (int c0 = 0; c0 < 128; c0 += 32) {
    __syncthreads();
#pragma unroll
    for (int i = 0; i < 2; ++i) {
      *reinterpret_cast<uint4*>(As + ast[i]) = *reinterpret_cast<const uint4*>(
          A + (size_t)(o0 + arow[i]) * 128 + c0 + aq[i] * 8);
    }
#pragma unroll
    for (int i = 0; i < 4; ++i) {
      const ushort* gp = Bq + (size_t)(c0 + bcg[i] * 4) * NTOK + n0 + bn[i];
      ushort4 hvec;
      hvec.x = gp[0];
      hvec.y = gp[NTOK];
      hvec.z = gp[2 * NTOK];
      hvec.w = gp[3 * NTOK];
      *reinterpret_cast<ushort4*>(Bt + bst[i]) = hvec;
    }
    __syncthreads();

    s16x8 af[4], bf[4];
#pragma unroll
    for (int mf = 0; mf < 4; ++mf)
      af[mf] = *reinterpret_cast<const s16x8*>(As + aoff[mf]);
#pragma unroll
    for (int nf = 0; nf < 4; ++nf)
      bf[nf] = *reinterpret_cast<const s16x8*>(Bt + boff[nf]);
#pragma unroll
    for (int mf = 0; mf < 4; ++mf)
#pragma unroll
      for (int nf = 0; nf < 4; ++nf)
        acc[mf][nf] = __builtin_amdgcn_mfma_f32_16x16x32_bf16(af[mf], bf[nf], acc[mf][nf], 0, 0, 0);
  }

  float* C = out + ((size_t)b * 256 + o0) * NTOK + n0;
#pragma unroll
  for (int mf = 0; mf < 4; ++mf) {
    const int row0 = wr * 64 + mf * 16 + lk * 4;
#pragma unroll
    for (int nf = 0; nf < 4; ++nf) {
      const int col = wc * 64 + nf * 16 + lm;
#pragma unroll
      for (int r = 0; r < 4; ++r) {
        const float bias = b_out[o0 + row0 + r];
        C[(size_t)(row0 + r) * NTOK + col] = acc[mf][nf][r] + bias;
      }
    }
  }
}

extern "C" void kernel_launch(void* const* d_in, const int* in_sizes, int n_in,
                              void* d_out, int out_size, void* d_ws, size_t ws_size,
                              hipStream_t stream) {
  const float* x     = (const float*)d_in[0];
  const float* w_qkv = (const float*)d_in[1];
  const float* w_out = (const float*)d_in[2];
  const float* b_out = (const float*)d_in[3];
  float* out = (float*)d_out;
  float* ws  = (float*)d_ws;

  float*  q_f32    = ws;                                 // 16777216 f32 (67MB)
  float*  ctx_part = ws + (size_t)16777216;              // 524288 f32 (2MB)
  ushort* whi      = (ushort*)ctx_part;                  // alias (live K1 only)
  ushort* wlo      = whi + 98304;
  ushort* kb       = (ushort*)(ws + (size_t)17301504);   // 16777216 bf16 (33.5MB)
  ushort* vb       = kb + (size_t)16777216;              // 33.5MB
  ushort* qb       = vb + (size_t)16777216;              // 33.5MB
  ushort* W2b      = qb + (size_t)16777216;              // 2MB

  k_cvt_w<<<96, 256, 0, stream>>>(w_qkv, whi, wlo);
  k_qkv_mfma<<<dim3(32, 3, 32), 256, 0, stream>>>(x, whi, wlo, q_f32, kb, vb);
  k_context_mfma<<<128, 256, 0, stream>>>(kb, vb, ctx_part);
  k_qsoftmax<<<4096, 256, 0, stream>>>(q_f32, qb);
  k_w2<<<32, 256, 0, stream>>>(ctx_part, w_out, W2b);
  k_out_mfma<<<dim3(32, 2, 32), 256, 0, stream>>>(qb, W2b, b_out, out);
}

// Round 6
// 209.658 us; speedup vs baseline: 2.8561x; 1.0952x over previous
//
#include <hip/hip_runtime.h>
#include <hip/hip_bf16.h>

#define NTOK 4096
#define SCALE 0.17677669529663687f  /* 32^-0.5 */

// 16B-chunk XOR swizzle within a 64B (32-ushort) LDS row (A tiles).
#define SWZ(r) ((((r) >> 1) ^ ((r) >> 3)) & 3)

using f32x4 = __attribute__((ext_vector_type(4))) float;
using s16x8 = __attribute__((ext_vector_type(8))) short;

__device__ __forceinline__ ushort bf_trunc(float f) {
  return (ushort)(__builtin_bit_cast(unsigned int, f) >> 16);
}
__device__ __forceinline__ float bf_to_f32(ushort h) {
  return __builtin_bit_cast(float, ((unsigned int)h) << 16);
}
__device__ __forceinline__ ushort bf_rne(float f) {
  unsigned int u = __builtin_bit_cast(unsigned int, f);
  u += 0x7FFFu + ((u >> 16) & 1u);
  return (ushort)(u >> 16);
}
// async global->LDS, 16B per lane; LDS dest = wave-uniform base + lane*16.
__device__ __forceinline__ void gl_lds16(const ushort* g, ushort* l) {
  __builtin_amdgcn_global_load_lds(
      (const __attribute__((address_space(1))) unsigned int*)g,
      (__attribute__((address_space(3))) unsigned int*)l, 16, 0, 0);
}

// ---------------------------------------------------------------------------
// K0: split w_qkv (384x256 f32) into bf16 hi/lo. grid 96 x 256.
// ---------------------------------------------------------------------------
__global__ __launch_bounds__(256) void k_cvt_w(const float* __restrict__ w,
                                               ushort* __restrict__ whi,
                                               ushort* __restrict__ wlo) {
  const int i = blockIdx.x * 256 + threadIdx.x;
  const float4 v = reinterpret_cast<const float4*>(w)[i];
  const float fv[4] = {v.x, v.y, v.z, v.w};
  ushort4 h, l;
  ushort* hp = &h.x;
  ushort* lp = &l.x;
#pragma unroll
  for (int j = 0; j < 4; ++j) {
    const ushort hh = bf_trunc(fv[j]);
    hp[j] = hh;
    lp[j] = bf_trunc(fv[j] - bf_to_f32(hh));
  }
  reinterpret_cast<ushort4*>(whi)[i] = h;
  reinterpret_cast<ushort4*>(wlo)[i] = l;
}

// ---------------------------------------------------------------------------
// K1: qkv = w_qkv @ x, MFMA bf16 2-term split (w hi/lo, x single bf16 RNE).
// 128x128 tile, BK=32, 4 waves, 24KB LDS single-buffer, T14 early B-prefetch.
// Epilogue: y==0 -> q bf16 (pre-softmax); y==1 -> softmax-over-d -> k bf16;
// y==2 -> v bf16. grid (32, 3, 32).
// ---------------------------------------------------------------------------
__global__ __launch_bounds__(256) void k_qkv_mfma(const float* __restrict__ x,
                                                  const ushort* __restrict__ whi,
                                                  const ushort* __restrict__ wlo,
                                                  ushort* __restrict__ qpre,
                                                  ushort* __restrict__ kb,
                                                  ushort* __restrict__ vb) {
  const int n0 = blockIdx.x * 128;
  const int o0 = blockIdx.y * 128;
  const int b  = blockIdx.z;
  const float* xb = x + (size_t)b * 256 * NTOK;

  __shared__ ushort Ah[4096];
  __shared__ ushort Al[4096];
  __shared__ ushort Bs[4096];

  const int t = threadIdx.x;
  const int lane = t & 63;
  const int wv = t >> 6;
  const int wr = wv >> 1, wc = wv & 1;
  const int lm = lane & 15;
  const int lk = lane >> 4;

  // fragment read offsets
  int aoff[4], boff[4];
#pragma unroll
  for (int mf = 0; mf < 4; ++mf) {
    const int ar = wr * 64 + mf * 16 + lm;
    aoff[mf] = ar * 32 + 8 * (lk ^ SWZ(ar));
  }
#pragma unroll
  for (int nf = 0; nf < 4; ++nf) {
    const int br = wc * 64 + nf * 16 + lm;
    boff[nf] = br * 32 + 8 * (lk ^ (br & 3));
  }
  // A gl_lds: slot s holds global chunk (row=s>>2, q=(s&3)^SWZ(row))
  const int as1 = t, as2 = t + 256;
  const int ar1 = as1 >> 2, gq1 = (as1 & 3) ^ SWZ(ar1);
  const int ar2 = as2 >> 2, gq2 = (as2 & 3) ^ SWZ(ar2);
  const size_t ga1 = (size_t)(o0 + ar1) * 256 + gq1 * 8;
  const size_t ga2 = (size_t)(o0 + ar2) * 256 + gq2 * 8;
  const int lbase1 = wv * 512;
  const int lbase2 = 2048 + wv * 512;
  // B staging: thread unit u = t + 256*i handles (n = u&127, c-oct = u>>7)
  int sst[2], sn[2], sco[2];
#pragma unroll
  for (int i = 0; i < 2; ++i) {
    const int u = t + 256 * i;
    sn[i] = u & 127;
    sco[i] = u >> 7;
    sst[i] = sn[i] * 32 + 8 * (sco[i] ^ (sn[i] & 3));
  }

  f32x4 acc[4][4];
#pragma unroll
  for (int i = 0; i < 4; ++i)
#pragma unroll
    for (int j = 0; j < 4; ++j) acc[i][j] = (f32x4){0.f, 0.f, 0.f, 0.f};

  // prologue: prefetch B(0)
  float pre[16];
#pragma unroll
  for (int i = 0; i < 2; ++i)
#pragma unroll
    for (int j = 0; j < 8; ++j)
      pre[i * 8 + j] = xb[(size_t)(sco[i] * 8 + j) * NTOK + n0 + sn[i]];

  for (int it = 0; it < 8; ++it) {
    const size_t c0 = (size_t)it * 32;
    // ---- stage phase ----
    gl_lds16(whi + ga1 + c0, Ah + lbase1);
    gl_lds16(whi + ga2 + c0, Ah + lbase2);
    gl_lds16(wlo + ga1 + c0, Al + lbase1);
    gl_lds16(wlo + ga2 + c0, Al + lbase2);
#pragma unroll
    for (int i = 0; i < 2; ++i) {
      s16x8 hv;
#pragma unroll
      for (int j = 0; j < 8; ++j) hv[j] = (short)bf_rne(pre[i * 8 + j]);
      *reinterpret_cast<s16x8*>(Bs + sst[i]) = hv;
    }
    __syncthreads();
    // ---- prefetch B(it+1): hides under MFMA phase ----
    if (it < 7) {
      const size_t c1 = c0 + 32;
#pragma unroll
      for (int i = 0; i < 2; ++i)
#pragma unroll
        for (int j = 0; j < 8; ++j)
          pre[i * 8 + j] = xb[(c1 + sco[i] * 8 + j) * NTOK + n0 + sn[i]];
    }
    // ---- MFMA phase ----
    s16x8 ah[4], al[4], bh[4];
#pragma unroll
    for (int mf = 0; mf < 4; ++mf) {
      ah[mf] = *reinterpret_cast<const s16x8*>(Ah + aoff[mf]);
      al[mf] = *reinterpret_cast<const s16x8*>(Al + aoff[mf]);
    }
#pragma unroll
    for (int nf = 0; nf < 4; ++nf)
      bh[nf] = *reinterpret_cast<const s16x8*>(Bs + boff[nf]);
#pragma unroll
    for (int mf = 0; mf < 4; ++mf)
#pragma unroll
      for (int nf = 0; nf < 4; ++nf) {
        acc[mf][nf] = __builtin_amdgcn_mfma_f32_16x16x32_bf16(ah[mf], bh[nf], acc[mf][nf], 0, 0, 0);
        acc[mf][nf] = __builtin_amdgcn_mfma_f32_16x16x32_bf16(al[mf], bh[nf], acc[mf][nf], 0, 0, 0);
      }
    __syncthreads();
  }

  // ---- epilogue ----
  if (blockIdx.y == 0) {
    ushort* C = qpre + (size_t)b * 128 * NTOK + n0;
#pragma unroll
    for (int mf = 0; mf < 4; ++mf) {
      const int row0 = wr * 64 + mf * 16 + lk * 4;
#pragma unroll
      for (int nf = 0; nf < 4; ++nf) {
        const int col = wc * 64 + nf * 16 + lm;
#pragma unroll
        for (int r = 0; r < 4; ++r)
          C[(size_t)(row0 + r) * NTOK + col] = bf_rne(acc[mf][nf][r]);
      }
    }
  } else if (blockIdx.y == 1) {
    // fused softmax over d: rows wr*64+mf*16+lk*4+r; head group g = mf>>1
#pragma unroll
    for (int nf = 0; nf < 4; ++nf) {
#pragma unroll
      for (int g = 0; g < 2; ++g) {
        float m = -1e30f;
#pragma unroll
        for (int mm = 0; mm < 2; ++mm)
#pragma unroll
          for (int r = 0; r < 4; ++r)
            m = fmaxf(m, acc[g * 2 + mm][nf][r]);
        m = fmaxf(m, __shfl_xor(m, 16, 64));
        m = fmaxf(m, __shfl_xor(m, 32, 64));
        float s = 0.f;
#pragma unroll
        for (int mm = 0; mm < 2; ++mm)
#pragma unroll
          for (int r = 0; r < 4; ++r) {
            const float e = __expf(acc[g * 2 + mm][nf][r] - m);
            acc[g * 2 + mm][nf][r] = e;
            s += e;
          }
        s += __shfl_xor(s, 16, 64);
        s += __shfl_xor(s, 32, 64);
        const float inv = 1.0f / s;
#pragma unroll
        for (int mm = 0; mm < 2; ++mm)
#pragma unroll
          for (int r = 0; r < 4; ++r) acc[g * 2 + mm][nf][r] *= inv;
      }
    }
    ushort* C = kb + (size_t)b * 128 * NTOK + n0;
#pragma unroll
    for (int mf = 0; mf < 4; ++mf) {
      const int row0 = wr * 64 + mf * 16 + lk * 4;
#pragma unroll
      for (int nf = 0; nf < 4; ++nf) {
        const int col = wc * 64 + nf * 16 + lm;
#pragma unroll
        for (int r = 0; r < 4; ++r)
          C[(size_t)(row0 + r) * NTOK + col] = bf_rne(acc[mf][nf][r]);
      }
    }
  } else {
    ushort* C = vb + (size_t)b * 128 * NTOK + n0;
#pragma unroll
    for (int mf = 0; mf < 4; ++mf) {
      const int row0 = wr * 64 + mf * 16 + lk * 4;
#pragma unroll
      for (int nf = 0; nf < 4; ++nf) {
        const int col = wc * 64 + nf * 16 + lm;
#pragma unroll
        for (int r = 0; r < 4; ++r)
          C[(size_t)(row0 + r) * NTOK + col] = bf_rne(acc[mf][nf][r]);
      }
    }
  }
}

// ---------------------------------------------------------------------------
// K2: context partials via bf16 MFMA. block = (b,h), 4 waves = 4 n-segments.
// ---------------------------------------------------------------------------
__global__ __launch_bounds__(256) void k_context_mfma(const ushort* __restrict__ kb,
                                                      const ushort* __restrict__ vb,
                                                      float* __restrict__ ctx_part) {
  const int bh = blockIdx.x;
  const int w = threadIdx.x >> 6;
  const int lane = threadIdx.x & 63;
  const int lm = lane & 15, lk = lane >> 4;
  const ushort* kp = kb + (size_t)bh * 32 * NTOK + (size_t)w * 1024;
  const ushort* vp = vb + (size_t)bh * 32 * NTOK + (size_t)w * 1024;
  f32x4 acc[2][2];
#pragma unroll
  for (int i = 0; i < 2; ++i)
#pragma unroll
    for (int j = 0; j < 2; ++j) acc[i][j] = (f32x4){0.f, 0.f, 0.f, 0.f};
#pragma unroll 4
  for (int ks = 0; ks < 32; ++ks) {
    const int coff = ks * 32 + lk * 8;
    const s16x8 a0 = *reinterpret_cast<const s16x8*>(kp + (size_t)lm * NTOK + coff);
    const s16x8 a1 = *reinterpret_cast<const s16x8*>(kp + (size_t)(16 + lm) * NTOK + coff);
    const s16x8 b0 = *reinterpret_cast<const s16x8*>(vp + (size_t)lm * NTOK + coff);
    const s16x8 b1 = *reinterpret_cast<const s16x8*>(vp + (size_t)(16 + lm) * NTOK + coff);
    acc[0][0] = __builtin_amdgcn_mfma_f32_16x16x32_bf16(a0, b0, acc[0][0], 0, 0, 0);
    acc[0][1] = __builtin_amdgcn_mfma_f32_16x16x32_bf16(a0, b1, acc[0][1], 0, 0, 0);
    acc[1][0] = __builtin_amdgcn_mfma_f32_16x16x32_bf16(a1, b0, acc[1][0], 0, 0, 0);
    acc[1][1] = __builtin_amdgcn_mfma_f32_16x16x32_bf16(a1, b1, acc[1][1], 0, 0, 0);
  }
  float* op = ctx_part + ((size_t)bh * 4 + w) * 1024;
#pragma unroll
  for (int et = 0; et < 2; ++et)
#pragma unroll
    for (int dt = 0; dt < 2; ++dt)
#pragma unroll
      for (int r = 0; r < 4; ++r)
        op[(et * 16 + lk * 4 + r) * 32 + dt * 16 + lm] = acc[et][dt][r];
}

// ---------------------------------------------------------------------------
// K3: q' = softmax over n (bf16 in) * SCALE -> bf16. grid 4096.
// ---------------------------------------------------------------------------
__global__ __launch_bounds__(256) void k_qsoftmax(const ushort* __restrict__ qpre,
                                                  ushort* __restrict__ qfin) {
  const int row = blockIdx.x;
  const ushort* p = qpre + (size_t)row * NTOK;
  ushort* op = qfin + (size_t)row * NTOK;
  const int t = threadIdx.x;
  float vals[16];
  float m = -1e30f;
#pragma unroll
  for (int i = 0; i < 2; ++i) {
    const s16x8 v = *reinterpret_cast<const s16x8*>(p + t * 8 + i * 2048);
#pragma unroll
    for (int j = 0; j < 8; ++j) {
      vals[i * 8 + j] = bf_to_f32((ushort)v[j]);
      m = fmaxf(m, vals[i * 8 + j]);
    }
  }
  __shared__ float red[4];
#pragma unroll
  for (int off = 32; off >= 1; off >>= 1) m = fmaxf(m, __shfl_down(m, off, 64));
  if ((t & 63) == 0) red[t >> 6] = m;
  __syncthreads();
  m = fmaxf(fmaxf(red[0], red[1]), fmaxf(red[2], red[3]));
  float s = 0.f;
#pragma unroll
  for (int i = 0; i < 16; ++i) {
    vals[i] = __expf(vals[i] - m);
    s += vals[i];
  }
  __syncthreads();
#pragma unroll
  for (int off = 32; off >= 1; off >>= 1) s += __shfl_down(s, off, 64);
  if ((t & 63) == 0) red[t >> 6] = s;
  __syncthreads();
  s = red[0] + red[1] + red[2] + red[3];
  const float f = SCALE / s;
#pragma unroll
  for (int i = 0; i < 2; ++i) {
    s16x8 o;
#pragma unroll
    for (int j = 0; j < 8; ++j) o[j] = (short)bf_rne(vals[i * 8 + j] * f);
    *reinterpret_cast<s16x8*>(op + t * 8 + i * 2048) = o;
  }
}

// ---------------------------------------------------------------------------
// K5: W2[b][o][h*32+e] = sum_d w_out[o][h*32+d] * ctx[b][h][e][d], -> bf16
// ---------------------------------------------------------------------------
__global__ __launch_bounds__(256) void k_w2(const float* __restrict__ ctx_part,
                                            const float* __restrict__ w_out,
                                            ushort* __restrict__ W2b) {
  const int b = blockIdx.x;
  const int t = threadIdx.x;
  __shared__ float ctx[4096];
#pragma unroll
  for (int i = 0; i < 16; ++i) {
    const int idx = t + 256 * i;
    const int h = idx >> 10, ed = idx & 1023;
    const float* cp = ctx_part + ((size_t)((b * 4 + h) * 4)) * 1024 + ed;
    ctx[idx] = cp[0] + cp[1024] + cp[2048] + cp[3072];
  }
  __syncthreads();
  const float* wrow = w_out + (size_t)t * 128;
  ushort* wout_row = W2b + ((size_t)b * 256 + t) * 128;
  float wv[32];
  for (int h = 0; h < 4; ++h) {
#pragma unroll
    for (int d = 0; d < 32; ++d) wv[d] = wrow[h * 32 + d];
#pragma unroll 4
    for (int e = 0; e < 32; ++e) {
      float a = 0.f;
#pragma unroll
      for (int d = 0; d < 32; ++d) a += wv[d] * ctx[h * 1024 + e * 32 + d];
      wout_row[h * 32 + e] = bf_rne(a);
    }
  }
}

// ---------------------------------------------------------------------------
// K6: out[b][o][n] = sum_c W2b[b][o][c] * q'[b][c][n] + b_out[o], bf16 MFMA.
// grid (32, 2, 32). Swizzled LDS, single-buffer.
// ---------------------------------------------------------------------------
__global__ __launch_bounds__(256) void k_out_mfma(const ushort* __restrict__ qb,
                                                  const ushort* __restrict__ W2b,
                                                  const float* __restrict__ b_out,
                                                  float* __restrict__ out) {
  const int n0 = blockIdx.x * 128;
  const int o0 = blockIdx.y * 128;
  const int b  = blockIdx.z;
  const ushort* A  = W2b + (size_t)b * 256 * 128;
  const ushort* Bq = qb + (size_t)b * 128 * NTOK;

  __shared__ ushort As[128 * 32];
  __shared__ ushort Bt[128 * 32];

  const int t = threadIdx.x;
  const int lane = t & 63;
  const int wv = t >> 6;
  const int wr = wv >> 1, wc = wv & 1;
  const int lm = lane & 15;
  const int lk = lane >> 4;

  int aoff[4], boff[4];
#pragma unroll
  for (int mf = 0; mf < 4; ++mf) {
    const int ar = wr * 64 + mf * 16 + lm;
    aoff[mf] = ar * 32 + 8 * (lk ^ SWZ(ar));
  }
#pragma unroll
  for (int nf = 0; nf < 4; ++nf) {
    const int br = wc * 64 + nf * 16 + lm;
    boff[nf] = br * 32 + 8 * (lk ^ SWZ(br));
  }
  int ast[2], arow[2], aq[2];
#pragma unroll
  for (int i = 0; i < 2; ++i) {
    const int ch = t + 256 * i;
    arow[i] = ch >> 2;
    aq[i] = ch & 3;
    ast[i] = arow[i] * 32 + 8 * (aq[i] ^ SWZ(arow[i]));
  }
  int bst[4], bn[4], bcg[4];
#pragma unroll
  for (int i = 0; i < 4; ++i) {
    const int idx = t + 256 * i;
    bn[i] = idx & 127;
    bcg[i] = idx >> 7;
    bst[i] = bn[i] * 32 + 8 * ((bcg[i] >> 1) ^ SWZ(bn[i])) + (bcg[i] & 1) * 4;
  }

  f32x4 acc[4][4];
#pragma unroll
  for (int i = 0; i < 4; ++i)
#pragma unroll
    for (int j = 0; j < 4; ++j) acc[i][j] = (f32x4){0.f, 0.f, 0.f, 0.f};

  for (int c0 = 0; c0 < 128; c0 += 32) {
    __syncthreads();
#pragma unroll
    for (int i = 0; i < 2; ++i) {
      *reinterpret_cast<uint4*>(As + ast[i]) = *reinterpret_cast<const uint4*>(
          A + (size_t)(o0 + arow[i]) * 128 + c0 + aq[i] * 8);
    }
#pragma unroll
    for (int i = 0; i < 4; ++i) {
      const ushort* gp = Bq + (size_t)(c0 + bcg[i] * 4) * NTOK + n0 + bn[i];
      ushort4 hvec;
      hvec.x = gp[0];
      hvec.y = gp[NTOK];
      hvec.z = gp[2 * NTOK];
      hvec.w = gp[3 * NTOK];
      *reinterpret_cast<ushort4*>(Bt + bst[i]) = hvec;
    }
    __syncthreads();

    s16x8 af[4], bf[4];
#pragma unroll
    for (int mf = 0; mf < 4; ++mf)
      af[mf] = *reinterpret_cast<const s16x8*>(As + aoff[mf]);
#pragma unroll
    for (int nf = 0; nf < 4; ++nf)
      bf[nf] = *reinterpret_cast<const s16x8*>(Bt + boff[nf]);
#pragma unroll
    for (int mf = 0; mf < 4; ++mf)
#pragma unroll
      for (int nf = 0; nf < 4; ++nf)
        acc[mf][nf] = __builtin_amdgcn_mfma_f32_16x16x32_bf16(af[mf], bf[nf], acc[mf][nf], 0, 0, 0);
  }

  float* C = out + ((size_t)b * 256 + o0) * NTOK + n0;
#pragma unroll
  for (int mf = 0; mf < 4; ++mf) {
    const int row0 = wr * 64 + mf * 16 + lk * 4;
#pragma unroll
    for (int nf = 0; nf < 4; ++nf) {
      const int col = wc * 64 + nf * 16 + lm;
#pragma unroll
      for (int r = 0; r < 4; ++r) {
        const float bias = b_out[o0 + row0 + r];
        C[(size_t)(row0 + r) * NTOK + col] = acc[mf][nf][r] + bias;
      }
    }
  }
}

extern "C" void kernel_launch(void* const* d_in, const int* in_sizes, int n_in,
                              void* d_out, int out_size, void* d_ws, size_t ws_size,
                              hipStream_t stream) {
  const float* x     = (const float*)d_in[0];
  const float* w_qkv = (const float*)d_in[1];
  const float* w_out = (const float*)d_in[2];
  const float* b_out = (const float*)d_in[3];
  float* out = (float*)d_out;

  ushort* qpre = (ushort*)d_ws;                      // 16777216 (33.5MB)
  ushort* qfin = qpre + (size_t)16777216;            // 33.5MB
  ushort* kb   = qpre + (size_t)2 * 16777216;        // 33.5MB
  ushort* vb   = qpre + (size_t)3 * 16777216;        // 33.5MB
  float*  ctx_part = (float*)(qpre + (size_t)4 * 16777216);  // 524288 f32 (2MB)
  ushort* whi  = (ushort*)ctx_part;                  // alias (live K1 only)
  ushort* wlo  = whi + 98304;
  ushort* W2b  = (ushort*)(ctx_part + 524288);       // 1048576 ushorts (2MB)

  k_cvt_w<<<96, 256, 0, stream>>>(w_qkv, whi, wlo);
  k_qkv_mfma<<<dim3(32, 3, 32), 256, 0, stream>>>(x, whi, wlo, qpre, kb, vb);
  k_context_mfma<<<128, 256, 0, stream>>>(kb, vb, ctx_part);
  k_qsoftmax<<<4096, 256, 0, stream>>>(qpre, qfin);
  k_w2<<<32, 256, 0, stream>>>(ctx_part, w_out, W2b);
  k_out_mfma<<<dim3(32, 2, 32), 256, 0, stream>>>(qfin, W2b, b_out, out);
}